// Round 12
// baseline (204.405 us; speedup 1.0000x reference)
//
#include <hip/hip_runtime.h>
#include <hip/hip_bf16.h>
#include <math.h>

#define EPS 1e-6f
#define LOG2E 1.44269504088896340736f

typedef __attribute__((ext_vector_type(8))) short short8;
typedef __attribute__((ext_vector_type(4))) short short4v;
typedef __attribute__((ext_vector_type(4))) float f32x4;

// f32 -> bf16 (round-to-nearest-even)
static __device__ __forceinline__ short f2bf(float x) {
    unsigned u = __builtin_bit_cast(unsigned, x);
    u += 0x7fffu + ((u >> 16) & 1u);
    return (short)(u >> 16);
}

typedef __attribute__((address_space(1))) const void gvoid_t;
typedef __attribute__((address_space(3))) void lvoid_t;
static __device__ __forceinline__ void gload_lds16(const void* g, void* l) {
    __builtin_amdgcn_global_load_lds((gvoid_t*)g, (lvoid_t*)l, 16, 0, 0);
}

// ---------------------------------------------------------------------------
// x f32 -> bf16, 8 elems/thread
// ---------------------------------------------------------------------------
__global__ __launch_bounds__(256) void cast_f32_bf16(const float* __restrict__ src,
                                                     short* __restrict__ dst, int n8) {
    const int i = blockIdx.x * 256 + threadIdx.x;
    if (i >= n8) return;
    const float4 a = reinterpret_cast<const float4*>(src)[2 * i];
    const float4 b = reinterpret_cast<const float4*>(src)[2 * i + 1];
    short8 o;
    o[0] = f2bf(a.x); o[1] = f2bf(a.y); o[2] = f2bf(a.z); o[3] = f2bf(a.w);
    o[4] = f2bf(b.x); o[5] = f2bf(b.y); o[6] = f2bf(b.z); o[7] = f2bf(b.w);
    reinterpret_cast<short8*>(dst)[i] = o;
}

// ---------------------------------------------------------------------------
// All four weight transposes in ONE dispatch.
// ---------------------------------------------------------------------------
__global__ __launch_bounds__(256) void transpose_cast_all(
    const float* __restrict__ Wq, const float* __restrict__ Wk,
    const float* __restrict__ Wv, const float* __restrict__ Wo,
    short* __restrict__ WT, short* __restrict__ WoT) {
    __shared__ short tl[64][65];
    int t = blockIdx.x;
    const float* src; short* dst; int N, nx;
    if (t < 256)      { src = Wq; dst = WT;                N = 1024; nx = 16; }
    else if (t < 320) { src = Wk; dst = WT + 1024 * 1024;  N = 256;  nx = 4;  t -= 256; }
    else if (t < 384) { src = Wv; dst = WT + 1280 * 1024;  N = 256;  nx = 4;  t -= 320; }
    else              { src = Wo; dst = WoT;               N = 1024; nx = 16; t -= 384; }
    const int n0 = (t % nx) * 64, k0 = (t / nx) * 64;
    const int tid = threadIdx.x;

    #pragma unroll
    for (int i = 0; i < 4; ++i) {
        const int kr = (tid >> 4) + i * 16;
        const int c4 = (tid & 15) * 4;
        const float4 v = *reinterpret_cast<const float4*>(
            &src[(size_t)(k0 + kr) * N + n0 + c4]);
        tl[kr][c4 + 0] = f2bf(v.x);
        tl[kr][c4 + 1] = f2bf(v.y);
        tl[kr][c4 + 2] = f2bf(v.z);
        tl[kr][c4 + 3] = f2bf(v.w);
    }
    __syncthreads();

    const int nr  = tid >> 2;
    const int kc0 = (tid & 3) * 16;
    short tmp[16];
    #pragma unroll
    for (int j = 0; j < 16; ++j) tmp[j] = tl[kc0 + j][nr];
    short8* outp = reinterpret_cast<short8*>(&dst[(size_t)(n0 + nr) * 1024 + k0 + kc0]);
    outp[0] = *reinterpret_cast<short8*>(&tmp[0]);
    outp[1] = *reinterpret_cast<short8*>(&tmp[8]);
}

// ---------------------------------------------------------------------------
// bf16 MFMA GEMM: C[M,N] f32 = A[M,K] bf16 · B^T[N,K] bf16.
// BM=128, BN=64, BK=32; 4 waves as 2M x 2N; wave tile 64x32; acc 4x2.
// ---------------------------------------------------------------------------
__global__ __launch_bounds__(256) void gemm_bf16(const short* __restrict__ A,
                                                 const short* __restrict__ BT,
                                                 float* __restrict__ C,
                                                 int M, int N, int K) {
    __shared__ short As[2][128 * 32];
    __shared__ short Bs[2][64 * 32];

    const int tid  = threadIdx.x;
    const int lane = tid & 63;
    const int w    = tid >> 6;
    const int lq = lane & 15, lh = lane >> 4;
    const int wm = w >> 1,   wn = w & 1;
    const size_t arow0 = (size_t)blockIdx.y * 128;
    const size_t brow0 = (size_t)blockIdx.x * 64;

    f32x4 acc[4][2];
    #pragma unroll
    for (int mi = 0; mi < 4; ++mi)
        #pragma unroll
        for (int ni = 0; ni < 2; ++ni) acc[mi][ni] = (f32x4){0.f, 0.f, 0.f, 0.f};

    const int NT = K >> 5;
    int cur = 0;

    auto STAGE = [&](int u, int k0) {
        #pragma unroll
        for (int i = 0; i < 2; ++i) {
            const int ch = w * 64 + i * 256 + lane;
            const int r = ch >> 2, c = ch & 3;
            const int cg = c ^ ((r >> 1) & 3);
            gload_lds16(A + (arow0 + r) * K + k0 + cg * 8,
                        &As[u][(w * 64 + i * 256) * 8]);
        }
        {
            const int r = tid >> 2, c = tid & 3;
            const int cg = c ^ ((r >> 1) & 3);
            gload_lds16(BT + (brow0 + r) * K + k0 + cg * 8, &Bs[u][tid * 8]);
        }
    };

    STAGE(0, 0);
    __syncthreads();

    for (int t = 0; t < NT; ++t) {
        if (t + 1 < NT) STAGE(cur ^ 1, (t + 1) << 5);

        short8 af[4], bf[2];
        #pragma unroll
        for (int mi = 0; mi < 4; ++mi) {
            const int r = wm * 64 + mi * 16 + lq;
            af[mi] = *reinterpret_cast<const short8*>(
                &As[cur][r * 32 + ((lh ^ ((r >> 1) & 3)) * 8)]);
        }
        #pragma unroll
        for (int ni = 0; ni < 2; ++ni) {
            const int r = wn * 32 + ni * 16 + lq;
            bf[ni] = *reinterpret_cast<const short8*>(
                &Bs[cur][r * 32 + ((lh ^ ((r >> 1) & 3)) * 8)]);
        }
        __builtin_amdgcn_s_setprio(1);
        #pragma unroll
        for (int mi = 0; mi < 4; ++mi)
            #pragma unroll
            for (int ni = 0; ni < 2; ++ni)
                acc[mi][ni] = __builtin_amdgcn_mfma_f32_16x16x32_bf16(
                    af[mi], bf[ni], acc[mi][ni], 0, 0, 0);
        __builtin_amdgcn_s_setprio(0);

        __syncthreads();
        cur ^= 1;
    }

    #pragma unroll
    for (int mi = 0; mi < 4; ++mi) {
        const size_t row = arow0 + wm * 64 + mi * 16 + lh * 4;
        #pragma unroll
        for (int ni = 0; ni < 2; ++ni) {
            const size_t col = brow0 + wn * 32 + ni * 16 + lq;
            #pragma unroll
            for (int i = 0; i < 4; ++i)
                C[(row + i) * N + col] = acc[mi][ni][i];
        }
    }
}

// ---------------------------------------------------------------------------
// RoPE + RMSNorm on qkv f32 [B,T,1536] -> bf16 head-major.
// ---------------------------------------------------------------------------
__global__ __launch_bounds__(256) void rope_rmsnorm_cast(
    const float* __restrict__ qkv, const float* __restrict__ cosb,
    const float* __restrict__ sinb, short* __restrict__ q16,
    short* __restrict__ k16, int B, int T) {
    const int lane = threadIdx.x & 63;
    const int wid  = threadIdx.x >> 6;
    const int row  = blockIdx.x * 4 + wid;
    const int bt = row / 20;
    const int h  = row % 20;
    const int b  = bt / T, t = bt % T;

    const float* src = (h < 16) ? qkv + (size_t)bt * 1536 + h * 64
                                : qkv + (size_t)bt * 1536 + 1024 + (h - 16) * 64;

    const int j = lane & 31;
    const float x1 = src[j];
    const float x2 = src[j + 32];
    const float c = cosb[t * 32 + j];
    const float s = sinb[t * 32 + j];
    float y = (lane < 32) ? (x1 * c + x2 * s) : (x2 * c - x1 * s);

    float ss = y * y;
    #pragma unroll
    for (int m = 1; m < 64; m <<= 1) ss += __shfl_xor(ss, m);
    const float r = rsqrtf(ss * (1.0f / 64.0f) + EPS);

    if (h < 16)
        q16[((size_t)(b * 16 + h) * T + t) * 64 + lane] = f2bf(y * r * (0.125f * LOG2E));
    else
        k16[((size_t)(b * 4 + (h - 16)) * T + t) * 64 + lane] = f2bf(y * r);
}

// ---------------------------------------------------------------------------
// v slice of qkv -> bf16 transposed + key-permuted vT16 [B,4,64,T]
// (within each 32-key group, true key (hi*16+g*4+i) stored at (g*8+hi*4+i))
// ---------------------------------------------------------------------------
__global__ __launch_bounds__(256) void vcast_transpose(
    const float* __restrict__ qkv, short* __restrict__ vT, int B, int T) {
    __shared__ short tl[64][65];
    const int tid = threadIdx.x;
    const int b = blockIdx.z, kvh = blockIdx.y, t0 = blockIdx.x * 64;

    #pragma unroll
    for (int i = 0; i < 4; ++i) {
        const int tr = (tid >> 4) + i * 16;
        const int d4 = (tid & 15) * 4;
        const float4 v4 = *reinterpret_cast<const float4*>(
            &qkv[(size_t)(b * T + t0 + tr) * 1536 + 1280 + kvh * 64 + d4]);
        tl[tr][d4 + 0] = f2bf(v4.x);
        tl[tr][d4 + 1] = f2bf(v4.y);
        tl[tr][d4 + 2] = f2bf(v4.z);
        tl[tr][d4 + 3] = f2bf(v4.w);
    }
    __syncthreads();

    const int dim = tid >> 2;
    const int tq  = (tid & 3) * 16;
    const int hi  = (tq >> 4) & 1;
    const int a32 = tq & 32;
    short tmp[16];
    #pragma unroll
    for (int j2 = 0; j2 < 16; ++j2) tmp[j2] = tl[tq + j2][dim];
    short* orow = &vT[((size_t)(b * 4 + kvh) * 64 + dim) * T + t0];
    #pragma unroll
    for (int g = 0; g < 4; ++g) {
        *reinterpret_cast<short4v*>(orow + a32 + g * 8 + hi * 4) =
            *reinterpret_cast<short4v*>(&tmp[g * 4]);
    }
}

// ---------------------------------------------------------------------------
// bf16 MFMA flash attention — R8's EXACT inner-loop structure (32-row qs
// strips, 2 waves x 16 q-rows, kmax in {2,4} via evenq, compile-time-indexed
// masks, same pack/PV/epilogue) with ONLY the load path changed: no LDS, no
// barriers — K/V fragments read directly from global (L2-resident; addresses
// proven equal to R8's staged LDS contents). Waves fully independent.
// ---------------------------------------------------------------------------
__global__ __launch_bounds__(128) void attn_mfma(
    const short* __restrict__ q16, const short* __restrict__ k16,
    const short* __restrict__ vT16, short* __restrict__ att16, int B, int T) {
    const int tid  = threadIdx.x;
    const int lane = tid & 63;
    const int w    = tid >> 6;          // 0..1
    const int lq   = lane & 15;
    const int lh   = lane >> 4;

    const int nbh = 16 * B;             // 32
    const int idx = blockIdx.x;
    const int qs  = (T >> 5) - 1 - idx / nbh;   // 63..0, longest-first
    const int bh  = idx % nbh;
    const int b   = bh >> 4, h = bh & 15;
    const int hk  = h >> 2;
    const int t0w = qs * 32 + w * 16;
    const int nt  = (qs >> 1) + 1;
    const bool evenq = !(qs & 1);       // last tile: keys 32..63 fully masked

    const short* qrow = q16 + ((size_t)(b * 16 + h) * T + t0w + lq) * 64;
    const short8 qf0 = *reinterpret_cast<const short8*>(qrow + lh * 8);
    const short8 qf1 = *reinterpret_cast<const short8*>(qrow + 32 + lh * 8);

    const short* kg = k16 + (size_t)(b * 4 + hk) * T * 64;
    const short* vg = vT16 + (size_t)(b * 4 + hk) * 64 * T;

    short8 ones;
    #pragma unroll
    for (int i = 0; i < 8; ++i) ones[i] = (short)0x3F80;   // bf16 1.0

    f32x4 yacc[4];
    #pragma unroll
    for (int dt = 0; dt < 4; ++dt) yacc[dt] = (f32x4){0.f, 0.f, 0.f, 0.f};
    f32x4 lacc = (f32x4){0.f, 0.f, 0.f, 0.f};

    for (int ti = 0; ti < nt; ++ti) {
        const int s0 = ti * 64;
        const bool last = (ti == nt - 1);
        const int kmax = (last && evenq) ? 2 : 4;   // skip fully-masked half

        // --- QK^T: S^T[key][q], K fragments direct from global (L2) ---
        f32x4 st[4];
        #pragma unroll
        for (int ks = 0; ks < 4; ++ks) if (ks < kmax) {
            const short* krow = kg + (size_t)(s0 + ks * 16 + lq) * 64;
            const short8 kfr0 = *reinterpret_cast<const short8*>(krow + lh * 8);
            const short8 kfr1 = *reinterpret_cast<const short8*>(krow + 32 + lh * 8);
            f32x4 a1 = (f32x4){0.f, 0.f, 0.f, 0.f};
            a1 = __builtin_amdgcn_mfma_f32_16x16x32_bf16(kfr0, qf0, a1, 0, 0, 0);
            a1 = __builtin_amdgcn_mfma_f32_16x16x32_bf16(kfr1, qf1, a1, 0, 0, 0);
            st[ks] = a1;
        }

        // --- causal mask on diagonal tile (compile-time st indices) ---
        if (last) {
            const int rloc = (qs & 1) * 32 + w * 16 + lq;
            #pragma unroll
            for (int ks = 0; ks < 4; ++ks) if (ks < kmax)
                #pragma unroll
                for (int i2 = 0; i2 < 4; ++i2)
                    if (ks * 16 + lh * 4 + i2 > rloc)
                        st[ks][i2] = -1e30f;
        }

        // --- p = exp2(s) directly (bounded scores); pack to bf16 ---
        union { short8 s8; __hip_bfloat162 h2[4]; } pf[2];
        #pragma unroll
        for (int ks2 = 0; ks2 < 2; ++ks2) if (ks2 * 2 < kmax) {
            #pragma unroll
            for (int ks = 2 * ks2; ks < 2 * ks2 + 2; ++ks)
                #pragma unroll
                for (int i2 = 0; i2 < 4; ++i2)
                    st[ks][i2] = exp2f(st[ks][i2]);
            pf[ks2].h2[0] = __float22bfloat162_rn(float2{st[2 * ks2][0], st[2 * ks2][1]});
            pf[ks2].h2[1] = __float22bfloat162_rn(float2{st[2 * ks2][2], st[2 * ks2][3]});
            pf[ks2].h2[2] = __float22bfloat162_rn(float2{st[2 * ks2 + 1][0], st[2 * ks2 + 1][1]});
            pf[ks2].h2[3] = __float22bfloat162_rn(float2{st[2 * ks2 + 1][2], st[2 * ks2 + 1][3]});
        }

        // --- PV + l (ones-fragment MFMA), V^T direct from global (L2) ---
        __builtin_amdgcn_s_setprio(1);
        #pragma unroll
        for (int ks2 = 0; ks2 < 2; ++ks2) if (ks2 * 2 < kmax)
            lacc = __builtin_amdgcn_mfma_f32_16x16x32_bf16(ones, pf[ks2].s8, lacc, 0, 0, 0);
        #pragma unroll
        for (int dt = 0; dt < 4; ++dt) {
            const short* vrow = vg + (size_t)(dt * 16 + lq) * T + s0;
            #pragma unroll
            for (int ks2 = 0; ks2 < 2; ++ks2) if (ks2 * 2 < kmax) {
                const short8 vf = *reinterpret_cast<const short8*>(
                    vrow + (ks2 * 4 + lh) * 8);
                yacc[dt] = __builtin_amdgcn_mfma_f32_16x16x32_bf16(
                    vf, pf[ks2].s8, yacc[dt], 0, 0, 0);
            }
        }
        __builtin_amdgcn_s_setprio(0);
    }

    // --- epilogue ---
    const float inv = 1.f / lacc[0];
    short* orow = att16 + (((size_t)b * T + t0w + lq) * 16 + h) * 64;
    #pragma unroll
    for (int dt = 0; dt < 4; ++dt) {
        short4v o;
        o[0] = f2bf(yacc[dt][0] * inv);
        o[1] = f2bf(yacc[dt][1] * inv);
        o[2] = f2bf(yacc[dt][2] * inv);
        o[3] = f2bf(yacc[dt][3] * inv);
        *reinterpret_cast<short4v*>(orow + dt * 16 + lh * 4) = o;
    }
}

// ---------------------------------------------------------------------------
extern "C" void kernel_launch(void* const* d_in, const int* in_sizes, int n_in,
                              void* d_out, int out_size, void* d_ws, size_t ws_size,
                              hipStream_t stream) {
    const float* x    = (const float*)d_in[0];
    const float* cosb = (const float*)d_in[1];
    const float* sinb = (const float*)d_in[2];
    const float* Wq   = (const float*)d_in[3];
    const float* Wk   = (const float*)d_in[4];
    const float* Wv   = (const float*)d_in[5];
    const float* Wo   = (const float*)d_in[6];
    float* out = (float*)d_out;

    const int B = 2, T = 2048;
    const int M = B * T;   // 4096
    const size_t MB = 1 << 20;

    char* wsb = (char*)d_ws;
    float* qkv  = (float*)(wsb);
    short* att16= (short*)(wsb);
    short* x16  = (short*)(wsb + 24 * MB);
    short* q16  = (short*)(wsb + 24 * MB);
    short* WT   = (short*)(wsb + 32 * MB);
    short* k16  = (short*)(wsb + 32 * MB);
    short* vT16 = (short*)(wsb + 34 * MB);
    short* WoT  = (short*)(wsb + 36 * MB);

    cast_f32_bf16<<<(M * 1024 / 8 + 255) / 256, 256, 0, stream>>>(x, x16, M * 1024 / 8);
    transpose_cast_all<<<640, 256, 0, stream>>>(Wq, Wk, Wv, Wo, WT, WoT);

    // QKV: 24 x 32 = 768 blocks (3/CU exact)
    gemm_bf16<<<dim3(1536 / 64, M / 128), 256, 0, stream>>>(x16, WT, qkv, M, 1536, 1024);

    rope_rmsnorm_cast<<<(B * T * 20) / 4, 256, 0, stream>>>(qkv, cosb, sinb, q16, k16, B, T);
    vcast_transpose<<<dim3(T / 64, 4, B), 256, 0, stream>>>(qkv, vT16, B, T);

    // LDS-free attention, R8 grid: (T/32)*32 = 2048 blocks x 128 threads
    attn_mfma<<<dim3((T / 32) * 16 * B), 128, 0, stream>>>(q16, k16, vT16, att16, B, T);

    // Wo: 16 x 32 = 512 blocks (2/CU exact)
    gemm_bf16<<<dim3(1024 / 64, M / 128), 256, 0, stream>>>(att16, WoT, out, M, 1024, 1024);
}

// Round 13
// 129.438 us; speedup vs baseline: 1.5792x; 1.5792x over previous
//
#include <hip/hip_runtime.h>
#include <hip/hip_bf16.h>
#include <math.h>

#define EPS 1e-6f
#define LOG2E 1.44269504088896340736f

typedef __attribute__((ext_vector_type(8))) short short8;
typedef __attribute__((ext_vector_type(4))) short short4v;
typedef __attribute__((ext_vector_type(4))) float f32x4;

// f32 -> bf16 (round-to-nearest-even)
static __device__ __forceinline__ short f2bf(float x) {
    unsigned u = __builtin_bit_cast(unsigned, x);
    u += 0x7fffu + ((u >> 16) & 1u);
    return (short)(u >> 16);
}

typedef __attribute__((address_space(1))) const void gvoid_t;
typedef __attribute__((address_space(3))) void lvoid_t;
static __device__ __forceinline__ void gload_lds16(const void* g, void* l) {
    __builtin_amdgcn_global_load_lds((gvoid_t*)g, (lvoid_t*)l, 16, 0, 0);
}

// ---------------------------------------------------------------------------
// x f32 -> bf16, 8 elems/thread
// ---------------------------------------------------------------------------
__global__ __launch_bounds__(256) void cast_f32_bf16(const float* __restrict__ src,
                                                     short* __restrict__ dst, int n8) {
    const int i = blockIdx.x * 256 + threadIdx.x;
    if (i >= n8) return;
    const float4 a = reinterpret_cast<const float4*>(src)[2 * i];
    const float4 b = reinterpret_cast<const float4*>(src)[2 * i + 1];
    short8 o;
    o[0] = f2bf(a.x); o[1] = f2bf(a.y); o[2] = f2bf(a.z); o[3] = f2bf(a.w);
    o[4] = f2bf(b.x); o[5] = f2bf(b.y); o[6] = f2bf(b.z); o[7] = f2bf(b.w);
    reinterpret_cast<short8*>(dst)[i] = o;
}

// ---------------------------------------------------------------------------
// All four weight transposes in ONE dispatch.
// ---------------------------------------------------------------------------
__global__ __launch_bounds__(256) void transpose_cast_all(
    const float* __restrict__ Wq, const float* __restrict__ Wk,
    const float* __restrict__ Wv, const float* __restrict__ Wo,
    short* __restrict__ WT, short* __restrict__ WoT) {
    __shared__ short tl[64][65];
    int t = blockIdx.x;
    const float* src; short* dst; int N, nx;
    if (t < 256)      { src = Wq; dst = WT;                N = 1024; nx = 16; }
    else if (t < 320) { src = Wk; dst = WT + 1024 * 1024;  N = 256;  nx = 4;  t -= 256; }
    else if (t < 384) { src = Wv; dst = WT + 1280 * 1024;  N = 256;  nx = 4;  t -= 320; }
    else              { src = Wo; dst = WoT;               N = 1024; nx = 16; t -= 384; }
    const int n0 = (t % nx) * 64, k0 = (t / nx) * 64;
    const int tid = threadIdx.x;

    #pragma unroll
    for (int i = 0; i < 4; ++i) {
        const int kr = (tid >> 4) + i * 16;
        const int c4 = (tid & 15) * 4;
        const float4 v = *reinterpret_cast<const float4*>(
            &src[(size_t)(k0 + kr) * N + n0 + c4]);
        tl[kr][c4 + 0] = f2bf(v.x);
        tl[kr][c4 + 1] = f2bf(v.y);
        tl[kr][c4 + 2] = f2bf(v.z);
        tl[kr][c4 + 3] = f2bf(v.w);
    }
    __syncthreads();

    const int nr  = tid >> 2;
    const int kc0 = (tid & 3) * 16;
    short tmp[16];
    #pragma unroll
    for (int j = 0; j < 16; ++j) tmp[j] = tl[kc0 + j][nr];
    short8* outp = reinterpret_cast<short8*>(&dst[(size_t)(n0 + nr) * 1024 + k0 + kc0]);
    outp[0] = *reinterpret_cast<short8*>(&tmp[0]);
    outp[1] = *reinterpret_cast<short8*>(&tmp[8]);
}

// ---------------------------------------------------------------------------
// bf16 MFMA GEMM: C[M,N] f32 = A[M,K] bf16 · B^T[N,K] bf16.
// BM=128, BN=64, BK=32; 4 waves as 2M x 2N; wave tile 64x32; acc 4x2.
// ---------------------------------------------------------------------------
__global__ __launch_bounds__(256) void gemm_bf16(const short* __restrict__ A,
                                                 const short* __restrict__ BT,
                                                 float* __restrict__ C,
                                                 int M, int N, int K) {
    __shared__ short As[2][128 * 32];
    __shared__ short Bs[2][64 * 32];

    const int tid  = threadIdx.x;
    const int lane = tid & 63;
    const int w    = tid >> 6;
    const int lq = lane & 15, lh = lane >> 4;
    const int wm = w >> 1,   wn = w & 1;
    const size_t arow0 = (size_t)blockIdx.y * 128;
    const size_t brow0 = (size_t)blockIdx.x * 64;

    f32x4 acc[4][2];
    #pragma unroll
    for (int mi = 0; mi < 4; ++mi)
        #pragma unroll
        for (int ni = 0; ni < 2; ++ni) acc[mi][ni] = (f32x4){0.f, 0.f, 0.f, 0.f};

    const int NT = K >> 5;
    int cur = 0;

    auto STAGE = [&](int u, int k0) {
        #pragma unroll
        for (int i = 0; i < 2; ++i) {
            const int ch = w * 64 + i * 256 + lane;
            const int r = ch >> 2, c = ch & 3;
            const int cg = c ^ ((r >> 1) & 3);
            gload_lds16(A + (arow0 + r) * K + k0 + cg * 8,
                        &As[u][(w * 64 + i * 256) * 8]);
        }
        {
            const int r = tid >> 2, c = tid & 3;
            const int cg = c ^ ((r >> 1) & 3);
            gload_lds16(BT + (brow0 + r) * K + k0 + cg * 8, &Bs[u][tid * 8]);
        }
    };

    STAGE(0, 0);
    __syncthreads();

    for (int t = 0; t < NT; ++t) {
        if (t + 1 < NT) STAGE(cur ^ 1, (t + 1) << 5);

        short8 af[4], bf[2];
        #pragma unroll
        for (int mi = 0; mi < 4; ++mi) {
            const int r = wm * 64 + mi * 16 + lq;
            af[mi] = *reinterpret_cast<const short8*>(
                &As[cur][r * 32 + ((lh ^ ((r >> 1) & 3)) * 8)]);
        }
        #pragma unroll
        for (int ni = 0; ni < 2; ++ni) {
            const int r = wn * 32 + ni * 16 + lq;
            bf[ni] = *reinterpret_cast<const short8*>(
                &Bs[cur][r * 32 + ((lh ^ ((r >> 1) & 3)) * 8)]);
        }
        __builtin_amdgcn_s_setprio(1);
        #pragma unroll
        for (int mi = 0; mi < 4; ++mi)
            #pragma unroll
            for (int ni = 0; ni < 2; ++ni)
                acc[mi][ni] = __builtin_amdgcn_mfma_f32_16x16x32_bf16(
                    af[mi], bf[ni], acc[mi][ni], 0, 0, 0);
        __builtin_amdgcn_s_setprio(0);

        __syncthreads();
        cur ^= 1;
    }

    #pragma unroll
    for (int mi = 0; mi < 4; ++mi) {
        const size_t row = arow0 + wm * 64 + mi * 16 + lh * 4;
        #pragma unroll
        for (int ni = 0; ni < 2; ++ni) {
            const size_t col = brow0 + wn * 32 + ni * 16 + lq;
            #pragma unroll
            for (int i = 0; i < 4; ++i)
                C[(row + i) * N + col] = acc[mi][ni][i];
        }
    }
}

// ---------------------------------------------------------------------------
// RoPE + RMSNorm on qkv f32 [B,T,1536] -> bf16 head-major.
// ---------------------------------------------------------------------------
__global__ __launch_bounds__(256) void rope_rmsnorm_cast(
    const float* __restrict__ qkv, const float* __restrict__ cosb,
    const float* __restrict__ sinb, short* __restrict__ q16,
    short* __restrict__ k16, int B, int T) {
    const int lane = threadIdx.x & 63;
    const int wid  = threadIdx.x >> 6;
    const int row  = blockIdx.x * 4 + wid;
    const int bt = row / 20;
    const int h  = row % 20;
    const int b  = bt / T, t = bt % T;

    const float* src = (h < 16) ? qkv + (size_t)bt * 1536 + h * 64
                                : qkv + (size_t)bt * 1536 + 1024 + (h - 16) * 64;

    const int j = lane & 31;
    const float x1 = src[j];
    const float x2 = src[j + 32];
    const float c = cosb[t * 32 + j];
    const float s = sinb[t * 32 + j];
    float y = (lane < 32) ? (x1 * c + x2 * s) : (x2 * c - x1 * s);

    float ss = y * y;
    #pragma unroll
    for (int m = 1; m < 64; m <<= 1) ss += __shfl_xor(ss, m);
    const float r = rsqrtf(ss * (1.0f / 64.0f) + EPS);

    if (h < 16)
        q16[((size_t)(b * 16 + h) * T + t) * 64 + lane] = f2bf(y * r * (0.125f * LOG2E));
    else
        k16[((size_t)(b * 4 + (h - 16)) * T + t) * 64 + lane] = f2bf(y * r);
}

// ---------------------------------------------------------------------------
// v slice of qkv -> bf16 transposed + key-permuted vT16 [B,4,64,T]
// (within each 32-key group, true key (hi*16+g*4+i) stored at (g*8+hi*4+i))
// ---------------------------------------------------------------------------
__global__ __launch_bounds__(256) void vcast_transpose(
    const float* __restrict__ qkv, short* __restrict__ vT, int B, int T) {
    __shared__ short tl[64][65];
    const int tid = threadIdx.x;
    const int b = blockIdx.z, kvh = blockIdx.y, t0 = blockIdx.x * 64;

    #pragma unroll
    for (int i = 0; i < 4; ++i) {
        const int tr = (tid >> 4) + i * 16;
        const int d4 = (tid & 15) * 4;
        const float4 v4 = *reinterpret_cast<const float4*>(
            &qkv[(size_t)(b * T + t0 + tr) * 1536 + 1280 + kvh * 64 + d4]);
        tl[tr][d4 + 0] = f2bf(v4.x);
        tl[tr][d4 + 1] = f2bf(v4.y);
        tl[tr][d4 + 2] = f2bf(v4.z);
        tl[tr][d4 + 3] = f2bf(v4.w);
    }
    __syncthreads();

    const int dim = tid >> 2;
    const int tq  = (tid & 3) * 16;
    const int hi  = (tq >> 4) & 1;
    const int a32 = tq & 32;
    short tmp[16];
    #pragma unroll
    for (int j2 = 0; j2 < 16; ++j2) tmp[j2] = tl[tq + j2][dim];
    short* orow = &vT[((size_t)(b * 4 + kvh) * 64 + dim) * T + t0];
    #pragma unroll
    for (int g = 0; g < 4; ++g) {
        *reinterpret_cast<short4v*>(orow + a32 + g * 8 + hi * 4) =
            *reinterpret_cast<short4v*>(&tmp[g * 4]);
    }
}

// ---------------------------------------------------------------------------
// bf16 MFMA flash attention — PAIRED complementary q-strips, SINGLE 16KB
// LDS buffer, static-max softmax. Block p of (b,h) owns strips qlo=p and
// qhi=63-p (uniform 33 tiles). Each wave: 16 rows of each strip; every
// staged K/V fragment is read ONCE and feeds both strips' MFMAs (LDS + L2
// bytes per q-row halve vs R8). l via ones-fragment MFMA.
// ---------------------------------------------------------------------------
__global__ __launch_bounds__(128) void attn_mfma(
    const short* __restrict__ q16, const short* __restrict__ k16,
    const short* __restrict__ vT16, short* __restrict__ att16, int B, int T) {
    __shared__ short Kt[64 * 64];
    __shared__ short Vt[64 * 64];

    const int tid  = threadIdx.x;
    const int lane = tid & 63;
    const int w    = tid >> 6;          // 0..1
    const int lq   = lane & 15;
    const int lh   = lane >> 4;

    const int idx = blockIdx.x;
    const int p   = idx & 31;           // pair index (fast)
    const int bh  = idx >> 5;
    const int b   = bh >> 4, h = bh & 15;
    const int hk  = h >> 2;
    const int NQ  = T >> 5;             // 64 strips of 32 rows
    const int qlo = p, qhi = NQ - 1 - p;
    const int nt_lo = (qlo >> 1) + 1;
    const int nt_hi = (qhi >> 1) + 1;   // nt_hi > nt_lo always
    const int t_lo = qlo * 32 + w * 16;
    const int t_hi = qhi * 32 + w * 16;

    const short* qbase = q16 + (size_t)(b * 16 + h) * T * 64;
    const short8 qlo0 = *reinterpret_cast<const short8*>(qbase + (t_lo + lq) * 64 + lh * 8);
    const short8 qlo1 = *reinterpret_cast<const short8*>(qbase + (t_lo + lq) * 64 + 32 + lh * 8);
    const short8 qhi0 = *reinterpret_cast<const short8*>(qbase + (t_hi + lq) * 64 + lh * 8);
    const short8 qhi1 = *reinterpret_cast<const short8*>(qbase + (t_hi + lq) * 64 + 32 + lh * 8);

    const short* kgbase = k16 + (size_t)(b * 4 + hk) * T * 64;
    const short* vgbase = vT16 + (size_t)(b * 4 + hk) * 64 * T;

    const int sr  = lane >> 3;          // 0..7
    const int sc  = lane & 7;
    const int scg = sc ^ sr;            // pre-swizzled global chunk

    short8 ones;
    #pragma unroll
    for (int i = 0; i < 8; ++i) ones[i] = (short)0x3F80;   // bf16 1.0

    f32x4 yhi[4], ylo[4];
    #pragma unroll
    for (int dt = 0; dt < 4; ++dt) {
        yhi[dt] = (f32x4){0.f, 0.f, 0.f, 0.f};
        ylo[dt] = (f32x4){0.f, 0.f, 0.f, 0.f};
    }
    f32x4 lhi = (f32x4){0.f, 0.f, 0.f, 0.f};
    f32x4 llo = (f32x4){0.f, 0.f, 0.f, 0.f};

    for (int ti = 0; ti < nt_hi; ++ti) {
        const int s0 = ti * 64;
        const bool lo_act  = (ti < nt_lo);
        const bool hi_last = (ti == nt_hi - 1);   // implies !lo_act
        const bool lo_last = (ti == nt_lo - 1);
        const int kmax_hi = (hi_last && !(qhi & 1)) ? 2 : 4;
        const int kmax_lo = (lo_last && !(qlo & 1)) ? 2 : 4;
        const int kmaxr   = lo_act ? 4 : kmax_hi;

        __syncthreads();                // everyone done reading previous tile
        #pragma unroll
        for (int p2 = 0; p2 < 4; ++p2) {
            const int r = w * 32 + p2 * 8 + sr;
            gload_lds16(kgbase + (size_t)(s0 + r) * 64 + scg * 8,
                        &Kt[(w * 32 + p2 * 8) * 64]);
            gload_lds16(vgbase + (size_t)r * T + s0 + scg * 8,
                        &Vt[(w * 32 + p2 * 8) * 64]);
        }
        __syncthreads();                // tile staged

        // --- QK^T both strips; each kfr read once, 4 MFMAs ---
        f32x4 sthi[4], stlo[4];
        __builtin_amdgcn_s_setprio(1);
        #pragma unroll
        for (int ks = 0; ks < 4; ++ks) if (ks < kmaxr) {
            const short8 kfr0 = *reinterpret_cast<const short8*>(
                (char*)Kt + (ks * 16 + lq) * 128 + ((lh ^ (lq & 7)) * 16));
            const short8 kfr1 = *reinterpret_cast<const short8*>(
                (char*)Kt + (ks * 16 + lq) * 128 + (((4 + lh) ^ (lq & 7)) * 16));
            if (ks < kmax_hi) {
                f32x4 a1 = (f32x4){0.f, 0.f, 0.f, 0.f};
                a1 = __builtin_amdgcn_mfma_f32_16x16x32_bf16(kfr0, qhi0, a1, 0, 0, 0);
                a1 = __builtin_amdgcn_mfma_f32_16x16x32_bf16(kfr1, qhi1, a1, 0, 0, 0);
                sthi[ks] = a1;
            }
            if (lo_act && ks < kmax_lo) {
                f32x4 b1 = (f32x4){0.f, 0.f, 0.f, 0.f};
                b1 = __builtin_amdgcn_mfma_f32_16x16x32_bf16(kfr0, qlo0, b1, 0, 0, 0);
                b1 = __builtin_amdgcn_mfma_f32_16x16x32_bf16(kfr1, qlo1, b1, 0, 0, 0);
                stlo[ks] = b1;
            }
        }
        __builtin_amdgcn_s_setprio(0);

        // --- causal masks on diagonal tiles ---
        if (hi_last) {
            const int rloc = (qhi & 1) * 32 + w * 16 + lq;
            #pragma unroll
            for (int ks = 0; ks < 4; ++ks) if (ks < kmax_hi)
                #pragma unroll
                for (int i2 = 0; i2 < 4; ++i2)
                    if (ks * 16 + lh * 4 + i2 > rloc) sthi[ks][i2] = -1e30f;
        }
        if (lo_act && lo_last) {
            const int rloc = (qlo & 1) * 32 + w * 16 + lq;
            #pragma unroll
            for (int ks = 0; ks < 4; ++ks) if (ks < kmax_lo)
                #pragma unroll
                for (int i2 = 0; i2 < 4; ++i2)
                    if (ks * 16 + lh * 4 + i2 > rloc) stlo[ks][i2] = -1e30f;
        }

        // --- p = exp2(s); pack to bf16 (hi then lo) ---
        union { short8 s8; __hip_bfloat162 h2[4]; } pfhi[2], pflo[2];
        #pragma unroll
        for (int ks2 = 0; ks2 < 2; ++ks2) if (ks2 * 2 < kmax_hi) {
            #pragma unroll
            for (int ks = 2 * ks2; ks < 2 * ks2 + 2; ++ks)
                #pragma unroll
                for (int i2 = 0; i2 < 4; ++i2)
                    sthi[ks][i2] = exp2f(sthi[ks][i2]);
            pfhi[ks2].h2[0] = __float22bfloat162_rn(float2{sthi[2 * ks2][0], sthi[2 * ks2][1]});
            pfhi[ks2].h2[1] = __float22bfloat162_rn(float2{sthi[2 * ks2][2], sthi[2 * ks2][3]});
            pfhi[ks2].h2[2] = __float22bfloat162_rn(float2{sthi[2 * ks2 + 1][0], sthi[2 * ks2 + 1][1]});
            pfhi[ks2].h2[3] = __float22bfloat162_rn(float2{sthi[2 * ks2 + 1][2], sthi[2 * ks2 + 1][3]});
        }
        if (lo_act) {
            #pragma unroll
            for (int ks2 = 0; ks2 < 2; ++ks2) if (ks2 * 2 < kmax_lo) {
                #pragma unroll
                for (int ks = 2 * ks2; ks < 2 * ks2 + 2; ++ks)
                    #pragma unroll
                    for (int i2 = 0; i2 < 4; ++i2)
                        stlo[ks][i2] = exp2f(stlo[ks][i2]);
                pflo[ks2].h2[0] = __float22bfloat162_rn(float2{stlo[2 * ks2][0], stlo[2 * ks2][1]});
                pflo[ks2].h2[1] = __float22bfloat162_rn(float2{stlo[2 * ks2][2], stlo[2 * ks2][3]});
                pflo[ks2].h2[2] = __float22bfloat162_rn(float2{stlo[2 * ks2 + 1][0], stlo[2 * ks2 + 1][1]});
                pflo[ks2].h2[3] = __float22bfloat162_rn(float2{stlo[2 * ks2 + 1][2], stlo[2 * ks2 + 1][3]});
            }
        }

        // --- l + PV; each vf read once, 2 MFMAs ---
        __builtin_amdgcn_s_setprio(1);
        #pragma unroll
        for (int ks2 = 0; ks2 < 2; ++ks2) {
            if (ks2 * 2 < kmax_hi)
                lhi = __builtin_amdgcn_mfma_f32_16x16x32_bf16(ones, pfhi[ks2].s8, lhi, 0, 0, 0);
            if (lo_act && ks2 * 2 < kmax_lo)
                llo = __builtin_amdgcn_mfma_f32_16x16x32_bf16(ones, pflo[ks2].s8, llo, 0, 0, 0);
        }
        #pragma unroll
        for (int dt = 0; dt < 4; ++dt) {
            const int rb = (dt * 16 + lq) * 128;
            const int sw = lq & 7;
            #pragma unroll
            for (int ks2 = 0; ks2 < 2; ++ks2) if (ks2 * 2 < kmaxr) {
                const short8 vf = *reinterpret_cast<const short8*>(
                    (const char*)Vt + rb + (((ks2 * 4 + lh) ^ sw) * 16));
                if (ks2 * 2 < kmax_hi)
                    yhi[dt] = __builtin_amdgcn_mfma_f32_16x16x32_bf16(
                        vf, pfhi[ks2].s8, yhi[dt], 0, 0, 0);
                if (lo_act && ks2 * 2 < kmax_lo)
                    ylo[dt] = __builtin_amdgcn_mfma_f32_16x16x32_bf16(
                        vf, pflo[ks2].s8, ylo[dt], 0, 0, 0);
            }
        }
        __builtin_amdgcn_s_setprio(0);
    }

    // --- epilogues ---
    const float invh = 1.f / lhi[0];
    short* orowh = att16 + (((size_t)b * T + t_hi + lq) * 16 + h) * 64;
    #pragma unroll
    for (int dt = 0; dt < 4; ++dt) {
        short4v o;
        o[0] = f2bf(yhi[dt][0] * invh);
        o[1] = f2bf(yhi[dt][1] * invh);
        o[2] = f2bf(yhi[dt][2] * invh);
        o[3] = f2bf(yhi[dt][3] * invh);
        *reinterpret_cast<short4v*>(orowh + dt * 16 + lh * 4) = o;
    }
    const float invl = 1.f / llo[0];
    short* orowl = att16 + (((size_t)b * T + t_lo + lq) * 16 + h) * 64;
    #pragma unroll
    for (int dt = 0; dt < 4; ++dt) {
        short4v o;
        o[0] = f2bf(ylo[dt][0] * invl);
        o[1] = f2bf(ylo[dt][1] * invl);
        o[2] = f2bf(ylo[dt][2] * invl);
        o[3] = f2bf(ylo[dt][3] * invl);
        *reinterpret_cast<short4v*>(orowl + dt * 16 + lh * 4) = o;
    }
}

// ---------------------------------------------------------------------------
extern "C" void kernel_launch(void* const* d_in, const int* in_sizes, int n_in,
                              void* d_out, int out_size, void* d_ws, size_t ws_size,
                              hipStream_t stream) {
    const float* x    = (const float*)d_in[0];
    const float* cosb = (const float*)d_in[1];
    const float* sinb = (const float*)d_in[2];
    const float* Wq   = (const float*)d_in[3];
    const float* Wk   = (const float*)d_in[4];
    const float* Wv   = (const float*)d_in[5];
    const float* Wo   = (const float*)d_in[6];
    float* out = (float*)d_out;

    const int B = 2, T = 2048;
    const int M = B * T;   // 4096
    const size_t MB = 1 << 20;

    char* wsb = (char*)d_ws;
    float* qkv  = (float*)(wsb);
    short* att16= (short*)(wsb);
    short* x16  = (short*)(wsb + 24 * MB);
    short* q16  = (short*)(wsb + 24 * MB);
    short* WT   = (short*)(wsb + 32 * MB);
    short* k16  = (short*)(wsb + 32 * MB);
    short* vT16 = (short*)(wsb + 34 * MB);
    short* WoT  = (short*)(wsb + 36 * MB);

    cast_f32_bf16<<<(M * 1024 / 8 + 255) / 256, 256, 0, stream>>>(x, x16, M * 1024 / 8);
    transpose_cast_all<<<640, 256, 0, stream>>>(Wq, Wk, Wv, Wo, WT, WoT);

    // QKV: 24 x 32 = 768 blocks (3/CU exact)
    gemm_bf16<<<dim3(1536 / 64, M / 128), 256, 0, stream>>>(x16, WT, qkv, M, 1536, 1024);

    rope_rmsnorm_cast<<<(B * T * 20) / 4, 256, 0, stream>>>(qkv, cosb, sinb, q16, k16, B, T);
    vcast_transpose<<<dim3(T / 64, 4, B), 256, 0, stream>>>(qkv, vT16, B, T);

    // paired static-max flash attention: 32 pairs x 32 (b,h) = 1024 blocks
    attn_mfma<<<dim3(32 * 16 * B), 128, 0, stream>>>(q16, k16, vT16, att16, B, T);

    // Wo: 16 x 32 = 512 blocks (2/CU exact)
    gemm_bf16<<<dim3(1024 / 64, M / 128), 256, 0, stream>>>(att16, WoT, out, M, 1024, 1024);
}

// Round 14
// 120.445 us; speedup vs baseline: 1.6971x; 1.0747x over previous
//
#include <hip/hip_runtime.h>
#include <hip/hip_bf16.h>
#include <math.h>

#define EPS 1e-6f
#define LOG2E 1.44269504088896340736f

typedef __attribute__((ext_vector_type(8))) short short8;
typedef __attribute__((ext_vector_type(4))) short short4v;
typedef __attribute__((ext_vector_type(4))) float f32x4;

// f32 -> bf16 (round-to-nearest-even)
static __device__ __forceinline__ short f2bf(float x) {
    unsigned u = __builtin_bit_cast(unsigned, x);
    u += 0x7fffu + ((u >> 16) & 1u);
    return (short)(u >> 16);
}

typedef __attribute__((address_space(1))) const void gvoid_t;
typedef __attribute__((address_space(3))) void lvoid_t;
static __device__ __forceinline__ void gload_lds16(const void* g, void* l) {
    __builtin_amdgcn_global_load_lds((gvoid_t*)g, (lvoid_t*)l, 16, 0, 0);
}

// ---------------------------------------------------------------------------
// x f32 -> bf16, 8 elems/thread
// ---------------------------------------------------------------------------
__global__ __launch_bounds__(256) void cast_f32_bf16(const float* __restrict__ src,
                                                     short* __restrict__ dst, int n8) {
    const int i = blockIdx.x * 256 + threadIdx.x;
    if (i >= n8) return;
    const float4 a = reinterpret_cast<const float4*>(src)[2 * i];
    const float4 b = reinterpret_cast<const float4*>(src)[2 * i + 1];
    short8 o;
    o[0] = f2bf(a.x); o[1] = f2bf(a.y); o[2] = f2bf(a.z); o[3] = f2bf(a.w);
    o[4] = f2bf(b.x); o[5] = f2bf(b.y); o[6] = f2bf(b.z); o[7] = f2bf(b.w);
    reinterpret_cast<short8*>(dst)[i] = o;
}

// ---------------------------------------------------------------------------
// All four weight transposes in ONE dispatch.
// ---------------------------------------------------------------------------
__global__ __launch_bounds__(256) void transpose_cast_all(
    const float* __restrict__ Wq, const float* __restrict__ Wk,
    const float* __restrict__ Wv, const float* __restrict__ Wo,
    short* __restrict__ WT, short* __restrict__ WoT) {
    __shared__ short tl[64][65];
    int t = blockIdx.x;
    const float* src; short* dst; int N, nx;
    if (t < 256)      { src = Wq; dst = WT;                N = 1024; nx = 16; }
    else if (t < 320) { src = Wk; dst = WT + 1024 * 1024;  N = 256;  nx = 4;  t -= 256; }
    else if (t < 384) { src = Wv; dst = WT + 1280 * 1024;  N = 256;  nx = 4;  t -= 320; }
    else              { src = Wo; dst = WoT;               N = 1024; nx = 16; t -= 384; }
    const int n0 = (t % nx) * 64, k0 = (t / nx) * 64;
    const int tid = threadIdx.x;

    #pragma unroll
    for (int i = 0; i < 4; ++i) {
        const int kr = (tid >> 4) + i * 16;
        const int c4 = (tid & 15) * 4;
        const float4 v = *reinterpret_cast<const float4*>(
            &src[(size_t)(k0 + kr) * N + n0 + c4]);
        tl[kr][c4 + 0] = f2bf(v.x);
        tl[kr][c4 + 1] = f2bf(v.y);
        tl[kr][c4 + 2] = f2bf(v.z);
        tl[kr][c4 + 3] = f2bf(v.w);
    }
    __syncthreads();

    const int nr  = tid >> 2;
    const int kc0 = (tid & 3) * 16;
    short tmp[16];
    #pragma unroll
    for (int j = 0; j < 16; ++j) tmp[j] = tl[kc0 + j][nr];
    short8* outp = reinterpret_cast<short8*>(&dst[(size_t)(n0 + nr) * 1024 + k0 + kc0]);
    outp[0] = *reinterpret_cast<short8*>(&tmp[0]);
    outp[1] = *reinterpret_cast<short8*>(&tmp[8]);
}

// ---------------------------------------------------------------------------
// bf16 MFMA GEMM: C[M,N] f32 = A[M,K] bf16 · B^T[N,K] bf16.
// BM=128, BN=64, BK=32; 4 waves as 2M x 2N; wave tile 64x32; acc 4x2.
// Grid: dim3(M/128, N/64) — linear id = m + (M/128)*n, so blocks sharing an
// A-panel (same m) are spaced M/128 = 32 apart -> same XCD (32 % 8 == 0).
// ---------------------------------------------------------------------------
__global__ __launch_bounds__(256) void gemm_bf16(const short* __restrict__ A,
                                                 const short* __restrict__ BT,
                                                 float* __restrict__ C,
                                                 int M, int N, int K) {
    __shared__ short As[2][128 * 32];
    __shared__ short Bs[2][64 * 32];

    const int tid  = threadIdx.x;
    const int lane = tid & 63;
    const int w    = tid >> 6;
    const int lq = lane & 15, lh = lane >> 4;
    const int wm = w >> 1,   wn = w & 1;
    const size_t arow0 = (size_t)blockIdx.x * 128;   // m-tile (x = fast dim)
    const size_t brow0 = (size_t)blockIdx.y * 64;    // n-tile

    f32x4 acc[4][2];
    #pragma unroll
    for (int mi = 0; mi < 4; ++mi)
        #pragma unroll
        for (int ni = 0; ni < 2; ++ni) acc[mi][ni] = (f32x4){0.f, 0.f, 0.f, 0.f};

    const int NT = K >> 5;
    int cur = 0;

    auto STAGE = [&](int u, int k0) {
        #pragma unroll
        for (int i = 0; i < 2; ++i) {
            const int ch = w * 64 + i * 256 + lane;
            const int r = ch >> 2, c = ch & 3;
            const int cg = c ^ ((r >> 1) & 3);
            gload_lds16(A + (arow0 + r) * K + k0 + cg * 8,
                        &As[u][(w * 64 + i * 256) * 8]);
        }
        {
            const int r = tid >> 2, c = tid & 3;
            const int cg = c ^ ((r >> 1) & 3);
            gload_lds16(BT + (brow0 + r) * K + k0 + cg * 8, &Bs[u][tid * 8]);
        }
    };

    STAGE(0, 0);
    __syncthreads();

    for (int t = 0; t < NT; ++t) {
        if (t + 1 < NT) STAGE(cur ^ 1, (t + 1) << 5);

        short8 af[4], bf[2];
        #pragma unroll
        for (int mi = 0; mi < 4; ++mi) {
            const int r = wm * 64 + mi * 16 + lq;
            af[mi] = *reinterpret_cast<const short8*>(
                &As[cur][r * 32 + ((lh ^ ((r >> 1) & 3)) * 8)]);
        }
        #pragma unroll
        for (int ni = 0; ni < 2; ++ni) {
            const int r = wn * 32 + ni * 16 + lq;
            bf[ni] = *reinterpret_cast<const short8*>(
                &Bs[cur][r * 32 + ((lh ^ ((r >> 1) & 3)) * 8)]);
        }
        __builtin_amdgcn_s_setprio(1);
        #pragma unroll
        for (int mi = 0; mi < 4; ++mi)
            #pragma unroll
            for (int ni = 0; ni < 2; ++ni)
                acc[mi][ni] = __builtin_amdgcn_mfma_f32_16x16x32_bf16(
                    af[mi], bf[ni], acc[mi][ni], 0, 0, 0);
        __builtin_amdgcn_s_setprio(0);

        __syncthreads();
        cur ^= 1;
    }

    #pragma unroll
    for (int mi = 0; mi < 4; ++mi) {
        const size_t row = arow0 + wm * 64 + mi * 16 + lh * 4;
        #pragma unroll
        for (int ni = 0; ni < 2; ++ni) {
            const size_t col = brow0 + wn * 32 + ni * 16 + lq;
            #pragma unroll
            for (int i = 0; i < 4; ++i)
                C[(row + i) * N + col] = acc[mi][ni][i];
        }
    }
}

// ---------------------------------------------------------------------------
// RoPE + RMSNorm on qkv f32 [B,T,1536] -> bf16 head-major.
// ---------------------------------------------------------------------------
__global__ __launch_bounds__(256) void rope_rmsnorm_cast(
    const float* __restrict__ qkv, const float* __restrict__ cosb,
    const float* __restrict__ sinb, short* __restrict__ q16,
    short* __restrict__ k16, int B, int T) {
    const int lane = threadIdx.x & 63;
    const int wid  = threadIdx.x >> 6;
    const int row  = blockIdx.x * 4 + wid;
    const int bt = row / 20;
    const int h  = row % 20;
    const int b  = bt / T, t = bt % T;

    const float* src = (h < 16) ? qkv + (size_t)bt * 1536 + h * 64
                                : qkv + (size_t)bt * 1536 + 1024 + (h - 16) * 64;

    const int j = lane & 31;
    const float x1 = src[j];
    const float x2 = src[j + 32];
    const float c = cosb[t * 32 + j];
    const float s = sinb[t * 32 + j];
    float y = (lane < 32) ? (x1 * c + x2 * s) : (x2 * c - x1 * s);

    float ss = y * y;
    #pragma unroll
    for (int m = 1; m < 64; m <<= 1) ss += __shfl_xor(ss, m);
    const float r = rsqrtf(ss * (1.0f / 64.0f) + EPS);

    if (h < 16)
        q16[((size_t)(b * 16 + h) * T + t) * 64 + lane] = f2bf(y * r * (0.125f * LOG2E));
    else
        k16[((size_t)(b * 4 + (h - 16)) * T + t) * 64 + lane] = f2bf(y * r);
}

// ---------------------------------------------------------------------------
// v slice of qkv -> bf16 transposed + key-permuted vT16 [B,4,64,T]
// (within each 32-key group, true key (hi*16+g*4+i) stored at (g*8+hi*4+i))
// ---------------------------------------------------------------------------
__global__ __launch_bounds__(256) void vcast_transpose(
    const float* __restrict__ qkv, short* __restrict__ vT, int B, int T) {
    __shared__ short tl[64][65];
    const int tid = threadIdx.x;
    const int b = blockIdx.z, kvh = blockIdx.y, t0 = blockIdx.x * 64;

    #pragma unroll
    for (int i = 0; i < 4; ++i) {
        const int tr = (tid >> 4) + i * 16;
        const int d4 = (tid & 15) * 4;
        const float4 v4 = *reinterpret_cast<const float4*>(
            &qkv[(size_t)(b * T + t0 + tr) * 1536 + 1280 + kvh * 64 + d4]);
        tl[tr][d4 + 0] = f2bf(v4.x);
        tl[tr][d4 + 1] = f2bf(v4.y);
        tl[tr][d4 + 2] = f2bf(v4.z);
        tl[tr][d4 + 3] = f2bf(v4.w);
    }
    __syncthreads();

    const int dim = tid >> 2;
    const int tq  = (tid & 3) * 16;
    const int hi  = (tq >> 4) & 1;
    const int a32 = tq & 32;
    short tmp[16];
    #pragma unroll
    for (int j2 = 0; j2 < 16; ++j2) tmp[j2] = tl[tq + j2][dim];
    short* orow = &vT[((size_t)(b * 4 + kvh) * 64 + dim) * T + t0];
    #pragma unroll
    for (int g = 0; g < 4; ++g) {
        *reinterpret_cast<short4v*>(orow + a32 + g * 8 + hi * 4) =
            *reinterpret_cast<short4v*>(&tmp[g * 4]);
    }
}

// ---------------------------------------------------------------------------
// bf16 MFMA flash attention — R8 champion structure VERBATIM (2 waves x 16
// q-rows, single 16KB LDS buffer, static-max softmax, l via ones-MFMA),
// with XCD-aware block mapping: idx = j*8 + g, g = b*4+hk. All blocks of a
// (b,hk) KV-group land on one XCD (round-robin assumption) -> K/V (1MB) and
// Q (1MB) L2-resident per XCD. j = LPT (descending qs) within group.
// ---------------------------------------------------------------------------
__global__ __launch_bounds__(128) void attn_mfma(
    const short* __restrict__ q16, const short* __restrict__ k16,
    const short* __restrict__ vT16, short* __restrict__ att16, int B, int T) {
    __shared__ short Kt[64 * 64];
    __shared__ short Vt[64 * 64];

    const int tid  = threadIdx.x;
    const int lane = tid & 63;
    const int w    = tid >> 6;          // 0..1
    const int lq   = lane & 15;
    const int lh   = lane >> 4;

    // --- XCD-aware decode: idx = j*8 + g ---
    const int idx = blockIdx.x;
    const int g   = idx & 7;            // b*4 + hk  (8 KV-groups = 8 XCDs)
    const int j   = idx >> 3;           // 0..255 within group
    const int b   = g >> 2;
    const int hk  = g & 3;
    const int qs  = (T >> 5) - 1 - (j >> 2);   // 63..0 (LPT within group)
    const int h   = hk * 4 + (j & 3);
    const int t0w = qs * 32 + w * 16;
    const int nt  = (qs >> 1) + 1;
    const bool evenq = !(qs & 1);       // last tile: keys 32..63 fully masked

    const short* qrow = q16 + ((size_t)(b * 16 + h) * T + t0w + lq) * 64;
    const short8 qf0 = *reinterpret_cast<const short8*>(qrow + lh * 8);
    const short8 qf1 = *reinterpret_cast<const short8*>(qrow + 32 + lh * 8);

    const short* kgbase = k16 + (size_t)(b * 4 + hk) * T * 64;
    const short* vgbase = vT16 + (size_t)(b * 4 + hk) * 64 * T;

    const int sr  = lane >> 3;          // 0..7
    const int sc  = lane & 7;
    const int scg = sc ^ sr;            // pre-swizzled global chunk

    short8 ones;
    #pragma unroll
    for (int i = 0; i < 8; ++i) ones[i] = (short)0x3F80;   // bf16 1.0

    f32x4 yacc[4];
    #pragma unroll
    for (int dt = 0; dt < 4; ++dt) yacc[dt] = (f32x4){0.f, 0.f, 0.f, 0.f};
    f32x4 lacc = (f32x4){0.f, 0.f, 0.f, 0.f};

    for (int ti = 0; ti < nt; ++ti) {
        const int s0 = ti * 64;
        const bool last = (ti == nt - 1);
        const int kmax = (last && evenq) ? 2 : 4;   // skip fully-masked half
        __syncthreads();
        #pragma unroll
        for (int p2 = 0; p2 < 4; ++p2) {
            const int r = w * 32 + p2 * 8 + sr;
            gload_lds16(kgbase + (size_t)(s0 + r) * 64 + scg * 8,
                        &Kt[(w * 32 + p2 * 8) * 64]);
            gload_lds16(vgbase + (size_t)r * T + s0 + scg * 8,
                        &Vt[(w * 32 + p2 * 8) * 64]);
        }
        __syncthreads();

        // --- QK^T: S^T[key][q] (log2 units; scale folded into q) ---
        f32x4 st[4];
        __builtin_amdgcn_s_setprio(1);
        #pragma unroll
        for (int ks = 0; ks < 4; ++ks) if (ks < kmax) {
            f32x4 a1 = (f32x4){0.f, 0.f, 0.f, 0.f};
            #pragma unroll
            for (int dk = 0; dk < 2; ++dk) {
                const short8 kfr = *reinterpret_cast<const short8*>(
                    (char*)Kt + (ks * 16 + lq) * 128 +
                    (((dk * 4 + lh) ^ (lq & 7)) * 16));
                a1 = __builtin_amdgcn_mfma_f32_16x16x32_bf16(
                    kfr, dk ? qf1 : qf0, a1, 0, 0, 0);
            }
            st[ks] = a1;
        }
        __builtin_amdgcn_s_setprio(0);

        // --- causal mask on diagonal tile ---
        if (last) {
            const int rloc = (qs & 1) * 32 + w * 16 + lq;
            #pragma unroll
            for (int ks = 0; ks < 4; ++ks) if (ks < kmax)
                #pragma unroll
                for (int i2 = 0; i2 < 4; ++i2)
                    if (ks * 16 + lh * 4 + i2 > rloc)
                        st[ks][i2] = -1e30f;
        }

        // --- p = exp2(s) directly (bounded scores); pack to bf16 ---
        union { short8 s8; __hip_bfloat162 h2[4]; } pf[2];
        #pragma unroll
        for (int ks2 = 0; ks2 < 2; ++ks2) if (ks2 * 2 < kmax) {
            #pragma unroll
            for (int ks = 2 * ks2; ks < 2 * ks2 + 2; ++ks)
                #pragma unroll
                for (int i2 = 0; i2 < 4; ++i2)
                    st[ks][i2] = exp2f(st[ks][i2]);
            pf[ks2].h2[0] = __float22bfloat162_rn(float2{st[2 * ks2][0], st[2 * ks2][1]});
            pf[ks2].h2[1] = __float22bfloat162_rn(float2{st[2 * ks2][2], st[2 * ks2][3]});
            pf[ks2].h2[2] = __float22bfloat162_rn(float2{st[2 * ks2 + 1][0], st[2 * ks2 + 1][1]});
            pf[ks2].h2[3] = __float22bfloat162_rn(float2{st[2 * ks2 + 1][2], st[2 * ks2 + 1][3]});
        }

        // --- PV + l (ones-fragment MFMA) ---
        __builtin_amdgcn_s_setprio(1);
        #pragma unroll
        for (int ks2 = 0; ks2 < 2; ++ks2) if (ks2 * 2 < kmax)
            lacc = __builtin_amdgcn_mfma_f32_16x16x32_bf16(ones, pf[ks2].s8, lacc, 0, 0, 0);
        #pragma unroll
        for (int dt = 0; dt < 4; ++dt) {
            const int rb = (dt * 16 + lq) * 128;
            const int sw = lq & 7;
            #pragma unroll
            for (int ks2 = 0; ks2 < 2; ++ks2) if (ks2 * 2 < kmax) {
                const short8 vf = *reinterpret_cast<const short8*>(
                    (const char*)Vt + rb + (((ks2 * 4 + lh) ^ sw) * 16));
                yacc[dt] = __builtin_amdgcn_mfma_f32_16x16x32_bf16(
                    vf, pf[ks2].s8, yacc[dt], 0, 0, 0);
            }
        }
        __builtin_amdgcn_s_setprio(0);
    }

    // --- epilogue ---
    const float inv = 1.f / lacc[0];
    short* orow = att16 + (((size_t)b * T + t0w + lq) * 16 + h) * 64;
    #pragma unroll
    for (int dt = 0; dt < 4; ++dt) {
        short4v o;
        o[0] = f2bf(yacc[dt][0] * inv);
        o[1] = f2bf(yacc[dt][1] * inv);
        o[2] = f2bf(yacc[dt][2] * inv);
        o[3] = f2bf(yacc[dt][3] * inv);
        *reinterpret_cast<short4v*>(orow + dt * 16 + lh * 4) = o;
    }
}

// ---------------------------------------------------------------------------
extern "C" void kernel_launch(void* const* d_in, const int* in_sizes, int n_in,
                              void* d_out, int out_size, void* d_ws, size_t ws_size,
                              hipStream_t stream) {
    const float* x    = (const float*)d_in[0];
    const float* cosb = (const float*)d_in[1];
    const float* sinb = (const float*)d_in[2];
    const float* Wq   = (const float*)d_in[3];
    const float* Wk   = (const float*)d_in[4];
    const float* Wv   = (const float*)d_in[5];
    const float* Wo   = (const float*)d_in[6];
    float* out = (float*)d_out;

    const int B = 2, T = 2048;
    const int M = B * T;   // 4096
    const size_t MB = 1 << 20;

    char* wsb = (char*)d_ws;
    float* qkv  = (float*)(wsb);
    short* att16= (short*)(wsb);
    short* x16  = (short*)(wsb + 24 * MB);
    short* q16  = (short*)(wsb + 24 * MB);
    short* WT   = (short*)(wsb + 32 * MB);
    short* k16  = (short*)(wsb + 32 * MB);
    short* vT16 = (short*)(wsb + 34 * MB);
    short* WoT  = (short*)(wsb + 36 * MB);

    cast_f32_bf16<<<(M * 1024 / 8 + 255) / 256, 256, 0, stream>>>(x, x16, M * 1024 / 8);
    transpose_cast_all<<<640, 256, 0, stream>>>(Wq, Wk, Wv, Wo, WT, WoT);

    // QKV: grid (M/128, N/64) -> same-A-panel blocks co-XCD
    gemm_bf16<<<dim3(M / 128, 1536 / 64), 256, 0, stream>>>(x16, WT, qkv, M, 1536, 1024);

    rope_rmsnorm_cast<<<(B * T * 20) / 4, 256, 0, stream>>>(qkv, cosb, sinb, q16, k16, B, T);
    vcast_transpose<<<dim3(T / 64, 4, B), 256, 0, stream>>>(qkv, vT16, B, T);

    // flash attention: R8 structure + XCD-aware block mapping (2048 blocks)
    attn_mfma<<<dim3((T / 32) * 16 * B), 128, 0, stream>>>(q16, k16, vT16, att16, B, T);

    // Wo: grid (M/128, N/64)
    gemm_bf16<<<dim3(M / 128, 1024 / 64), 256, 0, stream>>>(att16, WoT, out, M, 1024, 1024);
}

// Round 15
// 119.222 us; speedup vs baseline: 1.7145x; 1.0103x over previous
//
#include <hip/hip_runtime.h>
#include <hip/hip_bf16.h>
#include <math.h>

#define EPS 1e-6f
#define LOG2E 1.44269504088896340736f

typedef __attribute__((ext_vector_type(8))) short short8;
typedef __attribute__((ext_vector_type(4))) short short4v;
typedef __attribute__((ext_vector_type(4))) float f32x4;

// f32 -> bf16 (round-to-nearest-even)
static __device__ __forceinline__ short f2bf(float x) {
    unsigned u = __builtin_bit_cast(unsigned, x);
    u += 0x7fffu + ((u >> 16) & 1u);
    return (short)(u >> 16);
}
// bf16 -> f32
static __device__ __forceinline__ float bf2f(short s) {
    unsigned u = ((unsigned)(unsigned short)s) << 16;
    return __builtin_bit_cast(float, u);
}

typedef __attribute__((address_space(1))) const void gvoid_t;
typedef __attribute__((address_space(3))) void lvoid_t;
static __device__ __forceinline__ void gload_lds16(const void* g, void* l) {
    __builtin_amdgcn_global_load_lds((gvoid_t*)g, (lvoid_t*)l, 16, 0, 0);
}

// ---------------------------------------------------------------------------
// x f32 -> bf16, 8 elems/thread
// ---------------------------------------------------------------------------
__global__ __launch_bounds__(256) void cast_f32_bf16(const float* __restrict__ src,
                                                     short* __restrict__ dst, int n8) {
    const int i = blockIdx.x * 256 + threadIdx.x;
    if (i >= n8) return;
    const float4 a = reinterpret_cast<const float4*>(src)[2 * i];
    const float4 b = reinterpret_cast<const float4*>(src)[2 * i + 1];
    short8 o;
    o[0] = f2bf(a.x); o[1] = f2bf(a.y); o[2] = f2bf(a.z); o[3] = f2bf(a.w);
    o[4] = f2bf(b.x); o[5] = f2bf(b.y); o[6] = f2bf(b.z); o[7] = f2bf(b.w);
    reinterpret_cast<short8*>(dst)[i] = o;
}

// ---------------------------------------------------------------------------
// All four weight transposes in ONE dispatch.
// ---------------------------------------------------------------------------
__global__ __launch_bounds__(256) void transpose_cast_all(
    const float* __restrict__ Wq, const float* __restrict__ Wk,
    const float* __restrict__ Wv, const float* __restrict__ Wo,
    short* __restrict__ WT, short* __restrict__ WoT) {
    __shared__ short tl[64][65];
    int t = blockIdx.x;
    const float* src; short* dst; int N, nx;
    if (t < 256)      { src = Wq; dst = WT;                N = 1024; nx = 16; }
    else if (t < 320) { src = Wk; dst = WT + 1024 * 1024;  N = 256;  nx = 4;  t -= 256; }
    else if (t < 384) { src = Wv; dst = WT + 1280 * 1024;  N = 256;  nx = 4;  t -= 320; }
    else              { src = Wo; dst = WoT;               N = 1024; nx = 16; t -= 384; }
    const int n0 = (t % nx) * 64, k0 = (t / nx) * 64;
    const int tid = threadIdx.x;

    #pragma unroll
    for (int i = 0; i < 4; ++i) {
        const int kr = (tid >> 4) + i * 16;
        const int c4 = (tid & 15) * 4;
        const float4 v = *reinterpret_cast<const float4*>(
            &src[(size_t)(k0 + kr) * N + n0 + c4]);
        tl[kr][c4 + 0] = f2bf(v.x);
        tl[kr][c4 + 1] = f2bf(v.y);
        tl[kr][c4 + 2] = f2bf(v.z);
        tl[kr][c4 + 3] = f2bf(v.w);
    }
    __syncthreads();

    const int nr  = tid >> 2;
    const int kc0 = (tid & 3) * 16;
    short tmp[16];
    #pragma unroll
    for (int j = 0; j < 16; ++j) tmp[j] = tl[kc0 + j][nr];
    short8* outp = reinterpret_cast<short8*>(&dst[(size_t)(n0 + nr) * 1024 + k0 + kc0]);
    outp[0] = *reinterpret_cast<short8*>(&tmp[0]);
    outp[1] = *reinterpret_cast<short8*>(&tmp[8]);
}

// ---------------------------------------------------------------------------
// bf16 MFMA GEMM: C[M,N] = A[M,K] bf16 · B^T[N,K] bf16; OB=1 -> bf16 C,
// OB=0 -> f32 C. BM=128, BN=64, BK=32; 4 waves 2Mx2N; acc 4x2.
// Grid (M/128, N/64): same-A-panel blocks spaced 32 apart -> co-XCD.
// ---------------------------------------------------------------------------
template <int OB>
__global__ __launch_bounds__(256) void gemm_bf16(const short* __restrict__ A,
                                                 const short* __restrict__ BT,
                                                 float* __restrict__ Cf,
                                                 short* __restrict__ Cb,
                                                 int M, int N, int K) {
    __shared__ short As[2][128 * 32];
    __shared__ short Bs[2][64 * 32];

    const int tid  = threadIdx.x;
    const int lane = tid & 63;
    const int w    = tid >> 6;
    const int lq = lane & 15, lh = lane >> 4;
    const int wm = w >> 1,   wn = w & 1;
    const size_t arow0 = (size_t)blockIdx.x * 128;
    const size_t brow0 = (size_t)blockIdx.y * 64;

    f32x4 acc[4][2];
    #pragma unroll
    for (int mi = 0; mi < 4; ++mi)
        #pragma unroll
        for (int ni = 0; ni < 2; ++ni) acc[mi][ni] = (f32x4){0.f, 0.f, 0.f, 0.f};

    const int NT = K >> 5;
    int cur = 0;

    auto STAGE = [&](int u, int k0) {
        #pragma unroll
        for (int i = 0; i < 2; ++i) {
            const int ch = w * 64 + i * 256 + lane;
            const int r = ch >> 2, c = ch & 3;
            const int cg = c ^ ((r >> 1) & 3);
            gload_lds16(A + (arow0 + r) * K + k0 + cg * 8,
                        &As[u][(w * 64 + i * 256) * 8]);
        }
        {
            const int r = tid >> 2, c = tid & 3;
            const int cg = c ^ ((r >> 1) & 3);
            gload_lds16(BT + (brow0 + r) * K + k0 + cg * 8, &Bs[u][tid * 8]);
        }
    };

    STAGE(0, 0);
    __syncthreads();

    for (int t = 0; t < NT; ++t) {
        if (t + 1 < NT) STAGE(cur ^ 1, (t + 1) << 5);

        short8 af[4], bf[2];
        #pragma unroll
        for (int mi = 0; mi < 4; ++mi) {
            const int r = wm * 64 + mi * 16 + lq;
            af[mi] = *reinterpret_cast<const short8*>(
                &As[cur][r * 32 + ((lh ^ ((r >> 1) & 3)) * 8)]);
        }
        #pragma unroll
        for (int ni = 0; ni < 2; ++ni) {
            const int r = wn * 32 + ni * 16 + lq;
            bf[ni] = *reinterpret_cast<const short8*>(
                &Bs[cur][r * 32 + ((lh ^ ((r >> 1) & 3)) * 8)]);
        }
        __builtin_amdgcn_s_setprio(1);
        #pragma unroll
        for (int mi = 0; mi < 4; ++mi)
            #pragma unroll
            for (int ni = 0; ni < 2; ++ni)
                acc[mi][ni] = __builtin_amdgcn_mfma_f32_16x16x32_bf16(
                    af[mi], bf[ni], acc[mi][ni], 0, 0, 0);
        __builtin_amdgcn_s_setprio(0);

        __syncthreads();
        cur ^= 1;
    }

    #pragma unroll
    for (int mi = 0; mi < 4; ++mi) {
        const size_t row = arow0 + wm * 64 + mi * 16 + lh * 4;
        #pragma unroll
        for (int ni = 0; ni < 2; ++ni) {
            const size_t col = brow0 + wn * 32 + ni * 16 + lq;
            #pragma unroll
            for (int i = 0; i < 4; ++i) {
                if (OB) Cb[(row + i) * N + col] = f2bf(acc[mi][ni][i]);
                else    Cf[(row + i) * N + col] = acc[mi][ni][i];
            }
        }
    }
}

// ---------------------------------------------------------------------------
// FUSED prep: RoPE+RMSNorm (q,k) AND v transpose+permute, from bf16 qkv16.
// Blocks [0, B*T*5): rope rows (4 rows/block, one wave each).
// Blocks [B*T*5, B*T*5 + (T/64)*4*B): v 64x64 tile transpose.
//   q16 [B,16,T,64] (0.125*log2e folded), k16 [B,4,T,64],
//   vT16 [B,4,64,T] key-permuted: key (hi*16+g*4+i) at (g*8+hi*4+i).
// ---------------------------------------------------------------------------
__global__ __launch_bounds__(256) void rope_v_prep(
    const short* __restrict__ qkv16, const float* __restrict__ cosb,
    const float* __restrict__ sinb, short* __restrict__ q16,
    short* __restrict__ k16, short* __restrict__ vT, int B, int T) {
    const int NR = B * T * 5;   // rope blocks (4 rows each, B*T*20 rows)
    if ((int)blockIdx.x < NR) {
        const int lane = threadIdx.x & 63;
        const int wid  = threadIdx.x >> 6;
        const int row  = blockIdx.x * 4 + wid;
        const int bt = row / 20;
        const int h  = row % 20;
        const int b  = bt / T, t = bt % T;

        const short* src = (h < 16) ? qkv16 + (size_t)bt * 1536 + h * 64
                                    : qkv16 + (size_t)bt * 1536 + 1024 + (h - 16) * 64;

        const int j = lane & 31;
        const float x1 = bf2f(src[j]);
        const float x2 = bf2f(src[j + 32]);
        const float c = cosb[t * 32 + j];
        const float s = sinb[t * 32 + j];
        float y = (lane < 32) ? (x1 * c + x2 * s) : (x2 * c - x1 * s);

        float ss = y * y;
        #pragma unroll
        for (int m = 1; m < 64; m <<= 1) ss += __shfl_xor(ss, m);
        const float r = rsqrtf(ss * (1.0f / 64.0f) + EPS);

        if (h < 16)
            q16[((size_t)(b * 16 + h) * T + t) * 64 + lane] = f2bf(y * r * (0.125f * LOG2E));
        else
            k16[((size_t)(b * 4 + (h - 16)) * T + t) * 64 + lane] = f2bf(y * r);
        return;
    }

    // ---- v transpose path ----
    __shared__ short tl[64][65];
    const int vt = blockIdx.x - NR;          // [0, (T/64)*4*B)
    const int ntile = T >> 6;                // tiles per (b,kvh)
    const int b   = vt / (4 * ntile);
    const int kvh = (vt / ntile) & 3;
    const int t0  = (vt % ntile) * 64;
    const int tid = threadIdx.x;

    #pragma unroll
    for (int i = 0; i < 4; ++i) {
        const int tr = (tid >> 4) + i * 16;
        const int d4 = (tid & 15) * 4;
        const short4v v4 = *reinterpret_cast<const short4v*>(
            &qkv16[(size_t)(b * T + t0 + tr) * 1536 + 1280 + kvh * 64 + d4]);
        tl[tr][d4 + 0] = v4[0];
        tl[tr][d4 + 1] = v4[1];
        tl[tr][d4 + 2] = v4[2];
        tl[tr][d4 + 3] = v4[3];
    }
    __syncthreads();

    const int dim = tid >> 2;
    const int tq  = (tid & 3) * 16;
    const int hi  = (tq >> 4) & 1;
    const int a32 = tq & 32;
    short tmp[16];
    #pragma unroll
    for (int j2 = 0; j2 < 16; ++j2) tmp[j2] = tl[tq + j2][dim];
    short* orow = &vT[((size_t)(b * 4 + kvh) * 64 + dim) * T + t0];
    #pragma unroll
    for (int g = 0; g < 4; ++g) {
        *reinterpret_cast<short4v*>(orow + a32 + g * 8 + hi * 4) =
            *reinterpret_cast<short4v*>(&tmp[g * 4]);
    }
}

// ---------------------------------------------------------------------------
// bf16 MFMA flash attention — R8 champion structure + XCD-aware mapping
// (R14, verbatim): 2 waves x 16 q-rows, single 16KB LDS buffer, static-max
// softmax, l via ones-MFMA; idx = j*8 + g, g = b*4+hk.
// ---------------------------------------------------------------------------
__global__ __launch_bounds__(128) void attn_mfma(
    const short* __restrict__ q16, const short* __restrict__ k16,
    const short* __restrict__ vT16, short* __restrict__ att16, int B, int T) {
    __shared__ short Kt[64 * 64];
    __shared__ short Vt[64 * 64];

    const int tid  = threadIdx.x;
    const int lane = tid & 63;
    const int w    = tid >> 6;          // 0..1
    const int lq   = lane & 15;
    const int lh   = lane >> 4;

    const int idx = blockIdx.x;
    const int g   = idx & 7;            // b*4 + hk  (8 KV-groups = 8 XCDs)
    const int j   = idx >> 3;           // 0..255 within group
    const int b   = g >> 2;
    const int hk  = g & 3;
    const int qs  = (T >> 5) - 1 - (j >> 2);   // 63..0 (LPT within group)
    const int h   = hk * 4 + (j & 3);
    const int t0w = qs * 32 + w * 16;
    const int nt  = (qs >> 1) + 1;
    const bool evenq = !(qs & 1);       // last tile: keys 32..63 fully masked

    const short* qrow = q16 + ((size_t)(b * 16 + h) * T + t0w + lq) * 64;
    const short8 qf0 = *reinterpret_cast<const short8*>(qrow + lh * 8);
    const short8 qf1 = *reinterpret_cast<const short8*>(qrow + 32 + lh * 8);

    const short* kgbase = k16 + (size_t)(b * 4 + hk) * T * 64;
    const short* vgbase = vT16 + (size_t)(b * 4 + hk) * 64 * T;

    const int sr  = lane >> 3;          // 0..7
    const int sc  = lane & 7;
    const int scg = sc ^ sr;            // pre-swizzled global chunk

    short8 ones;
    #pragma unroll
    for (int i = 0; i < 8; ++i) ones[i] = (short)0x3F80;   // bf16 1.0

    f32x4 yacc[4];
    #pragma unroll
    for (int dt = 0; dt < 4; ++dt) yacc[dt] = (f32x4){0.f, 0.f, 0.f, 0.f};
    f32x4 lacc = (f32x4){0.f, 0.f, 0.f, 0.f};

    for (int ti = 0; ti < nt; ++ti) {
        const int s0 = ti * 64;
        const bool last = (ti == nt - 1);
        const int kmax = (last && evenq) ? 2 : 4;   // skip fully-masked half
        __syncthreads();
        #pragma unroll
        for (int p2 = 0; p2 < 4; ++p2) {
            const int r = w * 32 + p2 * 8 + sr;
            gload_lds16(kgbase + (size_t)(s0 + r) * 64 + scg * 8,
                        &Kt[(w * 32 + p2 * 8) * 64]);
            gload_lds16(vgbase + (size_t)r * T + s0 + scg * 8,
                        &Vt[(w * 32 + p2 * 8) * 64]);
        }
        __syncthreads();

        // --- QK^T: S^T[key][q] (log2 units; scale folded into q) ---
        f32x4 st[4];
        __builtin_amdgcn_s_setprio(1);
        #pragma unroll
        for (int ks = 0; ks < 4; ++ks) if (ks < kmax) {
            f32x4 a1 = (f32x4){0.f, 0.f, 0.f, 0.f};
            #pragma unroll
            for (int dk = 0; dk < 2; ++dk) {
                const short8 kfr = *reinterpret_cast<const short8*>(
                    (char*)Kt + (ks * 16 + lq) * 128 +
                    (((dk * 4 + lh) ^ (lq & 7)) * 16));
                a1 = __builtin_amdgcn_mfma_f32_16x16x32_bf16(
                    kfr, dk ? qf1 : qf0, a1, 0, 0, 0);
            }
            st[ks] = a1;
        }
        __builtin_amdgcn_s_setprio(0);

        // --- causal mask on diagonal tile ---
        if (last) {
            const int rloc = (qs & 1) * 32 + w * 16 + lq;
            #pragma unroll
            for (int ks = 0; ks < 4; ++ks) if (ks < kmax)
                #pragma unroll
                for (int i2 = 0; i2 < 4; ++i2)
                    if (ks * 16 + lh * 4 + i2 > rloc)
                        st[ks][i2] = -1e30f;
        }

        // --- p = exp2(s) directly (bounded scores); pack to bf16 ---
        union { short8 s8; __hip_bfloat162 h2[4]; } pf[2];
        #pragma unroll
        for (int ks2 = 0; ks2 < 2; ++ks2) if (ks2 * 2 < kmax) {
            #pragma unroll
            for (int ks = 2 * ks2; ks < 2 * ks2 + 2; ++ks)
                #pragma unroll
                for (int i2 = 0; i2 < 4; ++i2)
                    st[ks][i2] = exp2f(st[ks][i2]);
            pf[ks2].h2[0] = __float22bfloat162_rn(float2{st[2 * ks2][0], st[2 * ks2][1]});
            pf[ks2].h2[1] = __float22bfloat162_rn(float2{st[2 * ks2][2], st[2 * ks2][3]});
            pf[ks2].h2[2] = __float22bfloat162_rn(float2{st[2 * ks2 + 1][0], st[2 * ks2 + 1][1]});
            pf[ks2].h2[3] = __float22bfloat162_rn(float2{st[2 * ks2 + 1][2], st[2 * ks2 + 1][3]});
        }

        // --- PV + l (ones-fragment MFMA) ---
        __builtin_amdgcn_s_setprio(1);
        #pragma unroll
        for (int ks2 = 0; ks2 < 2; ++ks2) if (ks2 * 2 < kmax)
            lacc = __builtin_amdgcn_mfma_f32_16x16x32_bf16(ones, pf[ks2].s8, lacc, 0, 0, 0);
        #pragma unroll
        for (int dt = 0; dt < 4; ++dt) {
            const int rb = (dt * 16 + lq) * 128;
            const int sw = lq & 7;
            #pragma unroll
            for (int ks2 = 0; ks2 < 2; ++ks2) if (ks2 * 2 < kmax) {
                const short8 vf = *reinterpret_cast<const short8*>(
                    (const char*)Vt + rb + (((ks2 * 4 + lh) ^ sw) * 16));
                yacc[dt] = __builtin_amdgcn_mfma_f32_16x16x32_bf16(
                    vf, pf[ks2].s8, yacc[dt], 0, 0, 0);
            }
        }
        __builtin_amdgcn_s_setprio(0);
    }

    // --- epilogue ---
    const float inv = 1.f / lacc[0];
    short* orow = att16 + (((size_t)b * T + t0w + lq) * 16 + h) * 64;
    #pragma unroll
    for (int dt = 0; dt < 4; ++dt) {
        short4v o;
        o[0] = f2bf(yacc[dt][0] * inv);
        o[1] = f2bf(yacc[dt][1] * inv);
        o[2] = f2bf(yacc[dt][2] * inv);
        o[3] = f2bf(yacc[dt][3] * inv);
        *reinterpret_cast<short4v*>(orow + dt * 16 + lh * 4) = o;
    }
}

// ---------------------------------------------------------------------------
extern "C" void kernel_launch(void* const* d_in, const int* in_sizes, int n_in,
                              void* d_out, int out_size, void* d_ws, size_t ws_size,
                              hipStream_t stream) {
    const float* x    = (const float*)d_in[0];
    const float* cosb = (const float*)d_in[1];
    const float* sinb = (const float*)d_in[2];
    const float* Wq   = (const float*)d_in[3];
    const float* Wk   = (const float*)d_in[4];
    const float* Wv   = (const float*)d_in[5];
    const float* Wo   = (const float*)d_in[6];
    float* out = (float*)d_out;

    const int B = 2, T = 2048;
    const int M = B * T;   // 4096
    const size_t MB = 1 << 20;

    // workspace:
    //  [0,12M)  qkv16 bf16 [4096][1536]; att16 bf16 [4096][1024] overlays [0,8M)
    //  [24,32M) x16 bf16; q16 overlays after QKV GEMM
    //  [32,35M) WT bf16 [1536][1024]; k16 overlays [32,34M)
    //  [34,36M) vT16 bf16 [B,4,64,T]
    //  [36,38M) WoT bf16 [1024][1024]
    char* wsb = (char*)d_ws;
    short* qkv16 = (short*)(wsb);
    short* att16 = (short*)(wsb);
    short* x16   = (short*)(wsb + 24 * MB);
    short* q16   = (short*)(wsb + 24 * MB);
    short* WT    = (short*)(wsb + 32 * MB);
    short* k16   = (short*)(wsb + 32 * MB);
    short* vT16  = (short*)(wsb + 34 * MB);
    short* WoT   = (short*)(wsb + 36 * MB);

    cast_f32_bf16<<<(M * 1024 / 8 + 255) / 256, 256, 0, stream>>>(x, x16, M * 1024 / 8);
    transpose_cast_all<<<640, 256, 0, stream>>>(Wq, Wk, Wv, Wo, WT, WoT);

    // QKV: bf16 output; grid (M/128, N/64)
    gemm_bf16<1><<<dim3(M / 128, 1536 / 64), 256, 0, stream>>>(
        x16, WT, nullptr, qkv16, M, 1536, 1024);

    // fused rope+rms (q,k) and v transpose+permute, one dispatch
    rope_v_prep<<<B * T * 5 + (T / 64) * 4 * B, 256, 0, stream>>>(
        qkv16, cosb, sinb, q16, k16, vT16, B, T);

    // flash attention: R14 structure (2048 blocks x 128 threads)
    attn_mfma<<<dim3((T / 32) * 16 * B), 128, 0, stream>>>(q16, k16, vT16, att16, B, T);

    // Wo: f32 output; grid (M/128, N/64)
    gemm_bf16<0><<<dim3(M / 128, 1024 / 64), 256, 0, stream>>>(
        att16, WoT, out, nullptr, M, 1024, 1024);
}

// Round 16
// 113.240 us; speedup vs baseline: 1.8051x; 1.0528x over previous
//
#include <hip/hip_runtime.h>
#include <hip/hip_bf16.h>
#include <math.h>

#define EPS 1e-6f
#define LOG2E 1.44269504088896340736f

typedef __attribute__((ext_vector_type(8))) short short8;
typedef __attribute__((ext_vector_type(4))) short short4v;
typedef __attribute__((ext_vector_type(4))) float f32x4;

// f32 -> bf16 (round-to-nearest-even)
static __device__ __forceinline__ short f2bf(float x) {
    unsigned u = __builtin_bit_cast(unsigned, x);
    u += 0x7fffu + ((u >> 16) & 1u);
    return (short)(u >> 16);
}
// bf16 -> f32
static __device__ __forceinline__ float bf2f(short s) {
    unsigned u = ((unsigned)(unsigned short)s) << 16;
    return __builtin_bit_cast(float, u);
}

typedef __attribute__((address_space(1))) const void gvoid_t;
typedef __attribute__((address_space(3))) void lvoid_t;
static __device__ __forceinline__ void gload_lds16(const void* g, void* l) {
    __builtin_amdgcn_global_load_lds((gvoid_t*)g, (lvoid_t*)l, 16, 0, 0);
}

// ---------------------------------------------------------------------------
// Combined input prep: x cast (blocks [0,2048)) + all 4 weight transposes
// (blocks [2048, 2688)) in one dispatch.
// ---------------------------------------------------------------------------
__global__ __launch_bounds__(256) void prep_inputs(
    const float* __restrict__ x, const float* __restrict__ Wq,
    const float* __restrict__ Wk, const float* __restrict__ Wv,
    const float* __restrict__ Wo, short* __restrict__ x16,
    short* __restrict__ WT, short* __restrict__ WoT, int n8) {
    if ((int)blockIdx.x < 2048) {
        const int i = blockIdx.x * 256 + threadIdx.x;
        if (i >= n8) return;
        const float4 a = reinterpret_cast<const float4*>(x)[2 * i];
        const float4 b = reinterpret_cast<const float4*>(x)[2 * i + 1];
        short8 o;
        o[0] = f2bf(a.x); o[1] = f2bf(a.y); o[2] = f2bf(a.z); o[3] = f2bf(a.w);
        o[4] = f2bf(b.x); o[5] = f2bf(b.y); o[6] = f2bf(b.z); o[7] = f2bf(b.w);
        reinterpret_cast<short8*>(x16)[i] = o;
        return;
    }
    __shared__ short tl[64][65];
    int t = blockIdx.x - 2048;
    const float* src; short* dst; int N, nx;
    if (t < 256)      { src = Wq; dst = WT;                N = 1024; nx = 16; }
    else if (t < 320) { src = Wk; dst = WT + 1024 * 1024;  N = 256;  nx = 4;  t -= 256; }
    else if (t < 384) { src = Wv; dst = WT + 1280 * 1024;  N = 256;  nx = 4;  t -= 320; }
    else              { src = Wo; dst = WoT;               N = 1024; nx = 16; t -= 384; }
    const int n0 = (t % nx) * 64, k0 = (t / nx) * 64;
    const int tid = threadIdx.x;

    #pragma unroll
    for (int i = 0; i < 4; ++i) {
        const int kr = (tid >> 4) + i * 16;
        const int c4 = (tid & 15) * 4;
        const float4 v = *reinterpret_cast<const float4*>(
            &src[(size_t)(k0 + kr) * N + n0 + c4]);
        tl[kr][c4 + 0] = f2bf(v.x);
        tl[kr][c4 + 1] = f2bf(v.y);
        tl[kr][c4 + 2] = f2bf(v.z);
        tl[kr][c4 + 3] = f2bf(v.w);
    }
    __syncthreads();

    const int nr  = tid >> 2;
    const int kc0 = (tid & 3) * 16;
    short tmp[16];
    #pragma unroll
    for (int j = 0; j < 16; ++j) tmp[j] = tl[kc0 + j][nr];
    short8* outp = reinterpret_cast<short8*>(&dst[(size_t)(n0 + nr) * 1024 + k0 + kc0]);
    outp[0] = *reinterpret_cast<short8*>(&tmp[0]);
    outp[1] = *reinterpret_cast<short8*>(&tmp[8]);
}

// ---------------------------------------------------------------------------
// bf16 MFMA GEMM: C[M,N] = A[M,K] bf16 · B^T[N,K] bf16; OB=1 -> bf16 C.
// BM=128, BN=64, BK=64 (halves barrier count vs BK=32 — barrier-drain was
// the per-step cost; 16 MFMA/wave between barriers instead of 8).
// LDS 48KB (2buf) -> 3 blocks/CU. Staging/swizzle = attention's proven
// conflict-free 64-col pattern: 8-row groups, global chunk sc^sr, read
// chunk (dk*4+lh)^(lq&7). Grid (M/128, N/64): same-A blocks co-XCD.
// ---------------------------------------------------------------------------
template <int OB>
__global__ __launch_bounds__(256) void gemm_bf16(const short* __restrict__ A,
                                                 const short* __restrict__ BT,
                                                 float* __restrict__ Cf,
                                                 short* __restrict__ Cb,
                                                 int M, int N, int K) {
    __shared__ short As[2][128 * 64];
    __shared__ short Bs[2][64 * 64];

    const int tid  = threadIdx.x;
    const int lane = tid & 63;
    const int w    = tid >> 6;
    const int lq = lane & 15, lh = lane >> 4;
    const int wm = w >> 1,   wn = w & 1;
    const size_t arow0 = (size_t)blockIdx.x * 128;
    const size_t brow0 = (size_t)blockIdx.y * 64;

    const int sr  = lane >> 3;          // row within 8-group
    const int sc  = lane & 7;           // chunk
    const int scg = sc ^ sr;            // pre-swizzled global chunk

    f32x4 acc[4][2];
    #pragma unroll
    for (int mi = 0; mi < 4; ++mi)
        #pragma unroll
        for (int ni = 0; ni < 2; ++ni) acc[mi][ni] = (f32x4){0.f, 0.f, 0.f, 0.f};

    const int NT = K >> 6;

    auto STAGE = [&](int u, int k0) {
        // A: 128 rows = 16 row-groups of 8; 4 per wave
        #pragma unroll
        for (int i = 0; i < 4; ++i) {
            const int rg = w * 4 + i;
            gload_lds16(A + (arow0 + rg * 8 + sr) * K + k0 + scg * 8,
                        &As[u][rg * 8 * 64]);
        }
        // B: 64 rows = 8 row-groups; 2 per wave
        #pragma unroll
        for (int i = 0; i < 2; ++i) {
            const int rg = w * 2 + i;
            gload_lds16(BT + (brow0 + rg * 8 + sr) * K + k0 + scg * 8,
                        &Bs[u][rg * 8 * 64]);
        }
    };

    STAGE(0, 0);
    __syncthreads();
    int cur = 0;

    for (int t = 0; t < NT; ++t) {
        if (t + 1 < NT) STAGE(cur ^ 1, (t + 1) << 6);

        #pragma unroll
        for (int dk = 0; dk < 2; ++dk) {
            short8 af[4], bf[2];
            #pragma unroll
            for (int mi = 0; mi < 4; ++mi) {
                const int r = wm * 64 + mi * 16 + lq;
                af[mi] = *reinterpret_cast<const short8*>(
                    &As[cur][r * 64 + (((dk * 4 + lh) ^ (lq & 7)) * 8)]);
            }
            #pragma unroll
            for (int ni = 0; ni < 2; ++ni) {
                const int r = wn * 32 + ni * 16 + lq;
                bf[ni] = *reinterpret_cast<const short8*>(
                    &Bs[cur][r * 64 + (((dk * 4 + lh) ^ (lq & 7)) * 8)]);
            }
            __builtin_amdgcn_s_setprio(1);
            #pragma unroll
            for (int mi = 0; mi < 4; ++mi)
                #pragma unroll
                for (int ni = 0; ni < 2; ++ni)
                    acc[mi][ni] = __builtin_amdgcn_mfma_f32_16x16x32_bf16(
                        af[mi], bf[ni], acc[mi][ni], 0, 0, 0);
            __builtin_amdgcn_s_setprio(0);
        }

        __syncthreads();
        cur ^= 1;
    }

    #pragma unroll
    for (int mi = 0; mi < 4; ++mi) {
        const size_t row = arow0 + wm * 64 + mi * 16 + lh * 4;
        #pragma unroll
        for (int ni = 0; ni < 2; ++ni) {
            const size_t col = brow0 + wn * 32 + ni * 16 + lq;
            #pragma unroll
            for (int i = 0; i < 4; ++i) {
                if (OB) Cb[(row + i) * N + col] = f2bf(acc[mi][ni][i]);
                else    Cf[(row + i) * N + col] = acc[mi][ni][i];
            }
        }
    }
}

// ---------------------------------------------------------------------------
// FUSED prep: RoPE+RMSNorm (q,k) AND v transpose+permute, from bf16 qkv16.
// ---------------------------------------------------------------------------
__global__ __launch_bounds__(256) void rope_v_prep(
    const short* __restrict__ qkv16, const float* __restrict__ cosb,
    const float* __restrict__ sinb, short* __restrict__ q16,
    short* __restrict__ k16, short* __restrict__ vT, int B, int T) {
    const int NR = B * T * 5;
    if ((int)blockIdx.x < NR) {
        const int lane = threadIdx.x & 63;
        const int wid  = threadIdx.x >> 6;
        const int row  = blockIdx.x * 4 + wid;
        const int bt = row / 20;
        const int h  = row % 20;
        const int b  = bt / T, t = bt % T;

        const short* src = (h < 16) ? qkv16 + (size_t)bt * 1536 + h * 64
                                    : qkv16 + (size_t)bt * 1536 + 1024 + (h - 16) * 64;

        const int j = lane & 31;
        const float x1 = bf2f(src[j]);
        const float x2 = bf2f(src[j + 32]);
        const float c = cosb[t * 32 + j];
        const float s = sinb[t * 32 + j];
        float y = (lane < 32) ? (x1 * c + x2 * s) : (x2 * c - x1 * s);

        float ss = y * y;
        #pragma unroll
        for (int m = 1; m < 64; m <<= 1) ss += __shfl_xor(ss, m);
        const float r = rsqrtf(ss * (1.0f / 64.0f) + EPS);

        if (h < 16)
            q16[((size_t)(b * 16 + h) * T + t) * 64 + lane] = f2bf(y * r * (0.125f * LOG2E));
        else
            k16[((size_t)(b * 4 + (h - 16)) * T + t) * 64 + lane] = f2bf(y * r);
        return;
    }

    __shared__ short tl[64][65];
    const int vt = blockIdx.x - NR;
    const int ntile = T >> 6;
    const int b   = vt / (4 * ntile);
    const int kvh = (vt / ntile) & 3;
    const int t0  = (vt % ntile) * 64;
    const int tid = threadIdx.x;

    #pragma unroll
    for (int i = 0; i < 4; ++i) {
        const int tr = (tid >> 4) + i * 16;
        const int d4 = (tid & 15) * 4;
        const short4v v4 = *reinterpret_cast<const short4v*>(
            &qkv16[(size_t)(b * T + t0 + tr) * 1536 + 1280 + kvh * 64 + d4]);
        tl[tr][d4 + 0] = v4[0];
        tl[tr][d4 + 1] = v4[1];
        tl[tr][d4 + 2] = v4[2];
        tl[tr][d4 + 3] = v4[3];
    }
    __syncthreads();

    const int dim = tid >> 2;
    const int tq  = (tid & 3) * 16;
    const int hi  = (tq >> 4) & 1;
    const int a32 = tq & 32;
    short tmp[16];
    #pragma unroll
    for (int j2 = 0; j2 < 16; ++j2) tmp[j2] = tl[tq + j2][dim];
    short* orow = &vT[((size_t)(b * 4 + kvh) * 64 + dim) * T + t0];
    #pragma unroll
    for (int g = 0; g < 4; ++g) {
        *reinterpret_cast<short4v*>(orow + a32 + g * 8 + hi * 4) =
            *reinterpret_cast<short4v*>(&tmp[g * 4]);
    }
}

// ---------------------------------------------------------------------------
// bf16 MFMA flash attention — R14 champion verbatim.
// ---------------------------------------------------------------------------
__global__ __launch_bounds__(128) void attn_mfma(
    const short* __restrict__ q16, const short* __restrict__ k16,
    const short* __restrict__ vT16, short* __restrict__ att16, int B, int T) {
    __shared__ short Kt[64 * 64];
    __shared__ short Vt[64 * 64];

    const int tid  = threadIdx.x;
    const int lane = tid & 63;
    const int w    = tid >> 6;
    const int lq   = lane & 15;
    const int lh   = lane >> 4;

    const int idx = blockIdx.x;
    const int g   = idx & 7;
    const int j   = idx >> 3;
    const int b   = g >> 2;
    const int hk  = g & 3;
    const int qs  = (T >> 5) - 1 - (j >> 2);
    const int h   = hk * 4 + (j & 3);
    const int t0w = qs * 32 + w * 16;
    const int nt  = (qs >> 1) + 1;
    const bool evenq = !(qs & 1);

    const short* qrow = q16 + ((size_t)(b * 16 + h) * T + t0w + lq) * 64;
    const short8 qf0 = *reinterpret_cast<const short8*>(qrow + lh * 8);
    const short8 qf1 = *reinterpret_cast<const short8*>(qrow + 32 + lh * 8);

    const short* kgbase = k16 + (size_t)(b * 4 + hk) * T * 64;
    const short* vgbase = vT16 + (size_t)(b * 4 + hk) * 64 * T;

    const int sr  = lane >> 3;
    const int sc  = lane & 7;
    const int scg = sc ^ sr;

    short8 ones;
    #pragma unroll
    for (int i = 0; i < 8; ++i) ones[i] = (short)0x3F80;

    f32x4 yacc[4];
    #pragma unroll
    for (int dt = 0; dt < 4; ++dt) yacc[dt] = (f32x4){0.f, 0.f, 0.f, 0.f};
    f32x4 lacc = (f32x4){0.f, 0.f, 0.f, 0.f};

    for (int ti = 0; ti < nt; ++ti) {
        const int s0 = ti * 64;
        const bool last = (ti == nt - 1);
        const int kmax = (last && evenq) ? 2 : 4;
        __syncthreads();
        #pragma unroll
        for (int p2 = 0; p2 < 4; ++p2) {
            const int r = w * 32 + p2 * 8 + sr;
            gload_lds16(kgbase + (size_t)(s0 + r) * 64 + scg * 8,
                        &Kt[(w * 32 + p2 * 8) * 64]);
            gload_lds16(vgbase + (size_t)r * T + s0 + scg * 8,
                        &Vt[(w * 32 + p2 * 8) * 64]);
        }
        __syncthreads();

        f32x4 st[4];
        __builtin_amdgcn_s_setprio(1);
        #pragma unroll
        for (int ks = 0; ks < 4; ++ks) if (ks < kmax) {
            f32x4 a1 = (f32x4){0.f, 0.f, 0.f, 0.f};
            #pragma unroll
            for (int dk = 0; dk < 2; ++dk) {
                const short8 kfr = *reinterpret_cast<const short8*>(
                    (char*)Kt + (ks * 16 + lq) * 128 +
                    (((dk * 4 + lh) ^ (lq & 7)) * 16));
                a1 = __builtin_amdgcn_mfma_f32_16x16x32_bf16(
                    kfr, dk ? qf1 : qf0, a1, 0, 0, 0);
            }
            st[ks] = a1;
        }
        __builtin_amdgcn_s_setprio(0);

        if (last) {
            const int rloc = (qs & 1) * 32 + w * 16 + lq;
            #pragma unroll
            for (int ks = 0; ks < 4; ++ks) if (ks < kmax)
                #pragma unroll
                for (int i2 = 0; i2 < 4; ++i2)
                    if (ks * 16 + lh * 4 + i2 > rloc)
                        st[ks][i2] = -1e30f;
        }

        union { short8 s8; __hip_bfloat162 h2[4]; } pf[2];
        #pragma unroll
        for (int ks2 = 0; ks2 < 2; ++ks2) if (ks2 * 2 < kmax) {
            #pragma unroll
            for (int ks = 2 * ks2; ks < 2 * ks2 + 2; ++ks)
                #pragma unroll
                for (int i2 = 0; i2 < 4; ++i2)
                    st[ks][i2] = exp2f(st[ks][i2]);
            pf[ks2].h2[0] = __float22bfloat162_rn(float2{st[2 * ks2][0], st[2 * ks2][1]});
            pf[ks2].h2[1] = __float22bfloat162_rn(float2{st[2 * ks2][2], st[2 * ks2][3]});
            pf[ks2].h2[2] = __float22bfloat162_rn(float2{st[2 * ks2 + 1][0], st[2 * ks2 + 1][1]});
            pf[ks2].h2[3] = __float22bfloat162_rn(float2{st[2 * ks2 + 1][2], st[2 * ks2 + 1][3]});
        }

        __builtin_amdgcn_s_setprio(1);
        #pragma unroll
        for (int ks2 = 0; ks2 < 2; ++ks2) if (ks2 * 2 < kmax)
            lacc = __builtin_amdgcn_mfma_f32_16x16x32_bf16(ones, pf[ks2].s8, lacc, 0, 0, 0);
        #pragma unroll
        for (int dt = 0; dt < 4; ++dt) {
            const int rb = (dt * 16 + lq) * 128;
            const int sw = lq & 7;
            #pragma unroll
            for (int ks2 = 0; ks2 < 2; ++ks2) if (ks2 * 2 < kmax) {
                const short8 vf = *reinterpret_cast<const short8*>(
                    (const char*)Vt + rb + (((ks2 * 4 + lh) ^ sw) * 16));
                yacc[dt] = __builtin_amdgcn_mfma_f32_16x16x32_bf16(
                    vf, pf[ks2].s8, yacc[dt], 0, 0, 0);
            }
        }
        __builtin_amdgcn_s_setprio(0);
    }

    const float inv = 1.f / lacc[0];
    short* orow = att16 + (((size_t)b * T + t0w + lq) * 16 + h) * 64;
    #pragma unroll
    for (int dt = 0; dt < 4; ++dt) {
        short4v o;
        o[0] = f2bf(yacc[dt][0] * inv);
        o[1] = f2bf(yacc[dt][1] * inv);
        o[2] = f2bf(yacc[dt][2] * inv);
        o[3] = f2bf(yacc[dt][3] * inv);
        *reinterpret_cast<short4v*>(orow + dt * 16 + lh * 4) = o;
    }
}

// ---------------------------------------------------------------------------
extern "C" void kernel_launch(void* const* d_in, const int* in_sizes, int n_in,
                              void* d_out, int out_size, void* d_ws, size_t ws_size,
                              hipStream_t stream) {
    const float* x    = (const float*)d_in[0];
    const float* cosb = (const float*)d_in[1];
    const float* sinb = (const float*)d_in[2];
    const float* Wq   = (const float*)d_in[3];
    const float* Wk   = (const float*)d_in[4];
    const float* Wv   = (const float*)d_in[5];
    const float* Wo   = (const float*)d_in[6];
    float* out = (float*)d_out;

    const int B = 2, T = 2048;
    const int M = B * T;   // 4096
    const size_t MB = 1 << 20;

    char* wsb = (char*)d_ws;
    short* qkv16 = (short*)(wsb);
    short* att16 = (short*)(wsb);
    short* x16   = (short*)(wsb + 24 * MB);
    short* q16   = (short*)(wsb + 24 * MB);
    short* WT    = (short*)(wsb + 32 * MB);
    short* k16   = (short*)(wsb + 32 * MB);
    short* vT16  = (short*)(wsb + 34 * MB);
    short* WoT   = (short*)(wsb + 36 * MB);

    // x cast + all weight transposes, one dispatch
    prep_inputs<<<2048 + 640, 256, 0, stream>>>(x, Wq, Wk, Wv, Wo,
                                                x16, WT, WoT, M * 1024 / 8);

    // QKV: bf16 output; BK=64; grid (M/128, N/64)
    gemm_bf16<1><<<dim3(M / 128, 1536 / 64), 256, 0, stream>>>(
        x16, WT, nullptr, qkv16, M, 1536, 1024);

    // fused rope+rms (q,k) and v transpose+permute
    rope_v_prep<<<B * T * 5 + (T / 64) * 4 * B, 256, 0, stream>>>(
        qkv16, cosb, sinb, q16, k16, vT16, B, T);

    // flash attention (R14 champion)
    attn_mfma<<<dim3((T / 32) * 16 * B), 128, 0, stream>>>(q16, k16, vT16, att16, B, T);

    // Wo: f32 output; BK=64
    gemm_bf16<0><<<dim3(M / 128, 1024 / 64), 256, 0, stream>>>(
        att16, WoT, out, nullptr, M, 1024, 1024);
}

// Round 17
// 102.604 us; speedup vs baseline: 1.9922x; 1.1037x over previous
//
#include <hip/hip_runtime.h>
#include <hip/hip_bf16.h>
#include <math.h>

#define EPS 1e-6f
#define LOG2E 1.44269504088896340736f

typedef __attribute__((ext_vector_type(8))) short short8;
typedef __attribute__((ext_vector_type(4))) short short4v;
typedef __attribute__((ext_vector_type(4))) float f32x4;

// f32 -> bf16 (round-to-nearest-even)
static __device__ __forceinline__ short f2bf(float x) {
    unsigned u = __builtin_bit_cast(unsigned, x);
    u += 0x7fffu + ((u >> 16) & 1u);
    return (short)(u >> 16);
}
// bf16 -> f32
static __device__ __forceinline__ float bf2f(short s) {
    unsigned u = ((unsigned)(unsigned short)s) << 16;
    return __builtin_bit_cast(float, u);
}

typedef __attribute__((address_space(1))) const void gvoid_t;
typedef __attribute__((address_space(3))) void lvoid_t;
static __device__ __forceinline__ void gload_lds16(const void* g, void* l) {
    __builtin_amdgcn_global_load_lds((gvoid_t*)g, (lvoid_t*)l, 16, 0, 0);
}

// ---------------------------------------------------------------------------
// Combined input prep: x cast (blocks [0,2048)) + all 4 weight transposes
// (blocks [2048, 2688)) in one dispatch.
// ---------------------------------------------------------------------------
__global__ __launch_bounds__(256) void prep_inputs(
    const float* __restrict__ x, const float* __restrict__ Wq,
    const float* __restrict__ Wk, const float* __restrict__ Wv,
    const float* __restrict__ Wo, short* __restrict__ x16,
    short* __restrict__ WT, short* __restrict__ WoT, int n8) {
    if ((int)blockIdx.x < 2048) {
        const int i = blockIdx.x * 256 + threadIdx.x;
        if (i >= n8) return;
        const float4 a = reinterpret_cast<const float4*>(x)[2 * i];
        const float4 b = reinterpret_cast<const float4*>(x)[2 * i + 1];
        short8 o;
        o[0] = f2bf(a.x); o[1] = f2bf(a.y); o[2] = f2bf(a.z); o[3] = f2bf(a.w);
        o[4] = f2bf(b.x); o[5] = f2bf(b.y); o[6] = f2bf(b.z); o[7] = f2bf(b.w);
        reinterpret_cast<short8*>(x16)[i] = o;
        return;
    }
    __shared__ short tl[64][65];
    int t = blockIdx.x - 2048;
    const float* src; short* dst; int N, nx;
    if (t < 256)      { src = Wq; dst = WT;                N = 1024; nx = 16; }
    else if (t < 320) { src = Wk; dst = WT + 1024 * 1024;  N = 256;  nx = 4;  t -= 256; }
    else if (t < 384) { src = Wv; dst = WT + 1280 * 1024;  N = 256;  nx = 4;  t -= 320; }
    else              { src = Wo; dst = WoT;               N = 1024; nx = 16; t -= 384; }
    const int n0 = (t % nx) * 64, k0 = (t / nx) * 64;
    const int tid = threadIdx.x;

    #pragma unroll
    for (int i = 0; i < 4; ++i) {
        const int kr = (tid >> 4) + i * 16;
        const int c4 = (tid & 15) * 4;
        const float4 v = *reinterpret_cast<const float4*>(
            &src[(size_t)(k0 + kr) * N + n0 + c4]);
        tl[kr][c4 + 0] = f2bf(v.x);
        tl[kr][c4 + 1] = f2bf(v.y);
        tl[kr][c4 + 2] = f2bf(v.z);
        tl[kr][c4 + 3] = f2bf(v.w);
    }
    __syncthreads();

    const int nr  = tid >> 2;
    const int kc0 = (tid & 3) * 16;
    short tmp[16];
    #pragma unroll
    for (int j = 0; j < 16; ++j) tmp[j] = tl[kc0 + j][nr];
    short8* outp = reinterpret_cast<short8*>(&dst[(size_t)(n0 + nr) * 1024 + k0 + kc0]);
    outp[0] = *reinterpret_cast<short8*>(&tmp[0]);
    outp[1] = *reinterpret_cast<short8*>(&tmp[8]);
}

// ---------------------------------------------------------------------------
// FUSED QKV GEMM: [M,1024] x WT^T -> per-head outputs with RoPE/RMSNorm and
// V transpose applied IN THE EPILOGUE. BN=64 == head_dim, so each block's
// 128x64 output tile is one head slice: by 0-15 -> q16 (rope+rms+scale),
// by 16-19 -> k16 (rope+rms), by 20-23 -> vT16 (cast+transpose+key-permute).
// Main loop identical to BK=64 gemm (proven R16). Acc tile staged to LDS
// (stride-66 f32) for the cross-wave epilogue passes.
// ---------------------------------------------------------------------------
__global__ __launch_bounds__(256) void gemm_qkv_fused(
    const short* __restrict__ A, const short* __restrict__ BT,
    const float* __restrict__ cosb, const float* __restrict__ sinb,
    short* __restrict__ q16, short* __restrict__ k16, short* __restrict__ vT,
    int B, int T) {
    __shared__ short smem[2][(128 + 64) * 64];   // As | Bs, 48KB

    const int K = 1024;
    const int tid  = threadIdx.x;
    const int lane = tid & 63;
    const int w    = tid >> 6;
    const int lq = lane & 15, lh = lane >> 4;
    const int wm = w >> 1,   wn = w & 1;
    const size_t arow0 = (size_t)blockIdx.x * 128;
    const size_t brow0 = (size_t)blockIdx.y * 64;

    const int sr  = lane >> 3;
    const int sc  = lane & 7;
    const int scg = sc ^ sr;

    f32x4 acc[4][2];
    #pragma unroll
    for (int mi = 0; mi < 4; ++mi)
        #pragma unroll
        for (int ni = 0; ni < 2; ++ni) acc[mi][ni] = (f32x4){0.f, 0.f, 0.f, 0.f};

    const int NT = K >> 6;   // 16

    auto STAGE = [&](int u, int k0) {
        short* As = smem[u];
        short* Bs = smem[u] + 128 * 64;
        #pragma unroll
        for (int i = 0; i < 4; ++i) {
            const int rg = w * 4 + i;
            gload_lds16(A + (arow0 + rg * 8 + sr) * K + k0 + scg * 8,
                        &As[rg * 8 * 64]);
        }
        #pragma unroll
        for (int i = 0; i < 2; ++i) {
            const int rg = w * 2 + i;
            gload_lds16(BT + (brow0 + rg * 8 + sr) * K + k0 + scg * 8,
                        &Bs[rg * 8 * 64]);
        }
    };

    STAGE(0, 0);
    __syncthreads();
    int cur = 0;

    for (int t = 0; t < NT; ++t) {
        if (t + 1 < NT) STAGE(cur ^ 1, (t + 1) << 6);
        const short* As = smem[cur];
        const short* Bs = smem[cur] + 128 * 64;

        #pragma unroll
        for (int dk = 0; dk < 2; ++dk) {
            short8 af[4], bf[2];
            #pragma unroll
            for (int mi = 0; mi < 4; ++mi) {
                const int r = wm * 64 + mi * 16 + lq;
                af[mi] = *reinterpret_cast<const short8*>(
                    &As[r * 64 + (((dk * 4 + lh) ^ (lq & 7)) * 8)]);
            }
            #pragma unroll
            for (int ni = 0; ni < 2; ++ni) {
                const int r = wn * 32 + ni * 16 + lq;
                bf[ni] = *reinterpret_cast<const short8*>(
                    &Bs[r * 64 + (((dk * 4 + lh) ^ (lq & 7)) * 8)]);
            }
            __builtin_amdgcn_s_setprio(1);
            #pragma unroll
            for (int mi = 0; mi < 4; ++mi)
                #pragma unroll
                for (int ni = 0; ni < 2; ++ni)
                    acc[mi][ni] = __builtin_amdgcn_mfma_f32_16x16x32_bf16(
                        af[mi], bf[ni], acc[mi][ni], 0, 0, 0);
            __builtin_amdgcn_s_setprio(0);
        }

        __syncthreads();
        cur ^= 1;
    }

    // ---- epilogue: stash f32 tile [128][66-padded] in LDS ----
    float* fl = (float*)smem;   // 128*66*4 = 33792B <= 48KB
    #pragma unroll
    for (int mi = 0; mi < 4; ++mi) {
        const int row = wm * 64 + mi * 16 + lh * 4;
        #pragma unroll
        for (int ni = 0; ni < 2; ++ni) {
            const int col = wn * 32 + ni * 16 + lq;
            #pragma unroll
            for (int i = 0; i < 4; ++i)
                fl[(row + i) * 66 + col] = acc[mi][ni][i];
        }
    }
    __syncthreads();

    const int by = blockIdx.y;
    const int b  = (int)(arow0 / T);
    const int t0 = (int)(arow0 % T);

    if (by < 20) {
        // --- rope + rmsnorm; wave w handles rows w*32 .. w*32+31 ---
        const int j = lane & 31;
        for (int rr = 0; rr < 32; ++rr) {
            const int row = w * 32 + rr;
            const int t   = t0 + row;
            const float x1 = fl[row * 66 + j];
            const float x2 = fl[row * 66 + 32 + j];
            const float c = cosb[t * 32 + j];
            const float s = sinb[t * 32 + j];
            float y = (lane < 32) ? (x1 * c + x2 * s) : (x2 * c - x1 * s);
            float ss = y * y;
            #pragma unroll
            for (int m = 1; m < 64; m <<= 1) ss += __shfl_xor(ss, m);
            const float r = rsqrtf(ss * (1.0f / 64.0f) + EPS);
            if (by < 16)
                q16[((size_t)(b * 16 + by) * T + t) * 64 + lane] =
                    f2bf(y * r * (0.125f * LOG2E));
            else
                k16[((size_t)(b * 4 + (by - 16)) * T + t) * 64 + lane] =
                    f2bf(y * r);
        }
    } else {
        // --- v: cast + transpose + key-permute (two 64-row halves) ---
        const int kvh = by - 20;
        const int dim = tid >> 2;
        const int tq  = (tid & 3) * 16;
        const int hi  = (tq >> 4) & 1;
        const int a32 = tq & 32;
        short* orow = vT + ((size_t)(b * 4 + kvh) * 64 + dim) * T + t0;
        #pragma unroll
        for (int th = 0; th < 2; ++th) {
            short tmp[16];
            #pragma unroll
            for (int j2 = 0; j2 < 16; ++j2)
                tmp[j2] = f2bf(fl[(th * 64 + tq + j2) * 66 + dim]);
            #pragma unroll
            for (int g = 0; g < 4; ++g)
                *reinterpret_cast<short4v*>(orow + th * 64 + a32 + g * 8 + hi * 4) =
                    *reinterpret_cast<short4v*>(&tmp[g * 4]);
        }
    }
}

// ---------------------------------------------------------------------------
// bf16 MFMA GEMM (Wo): C f32 = A bf16 · B^T bf16. BK=64 (R16 proven).
// ---------------------------------------------------------------------------
__global__ __launch_bounds__(256) void gemm_wo(const short* __restrict__ A,
                                               const short* __restrict__ BT,
                                               float* __restrict__ C,
                                               int M, int N, int K) {
    __shared__ short smem[2][(128 + 64) * 64];

    const int tid  = threadIdx.x;
    const int lane = tid & 63;
    const int w    = tid >> 6;
    const int lq = lane & 15, lh = lane >> 4;
    const int wm = w >> 1,   wn = w & 1;
    const size_t arow0 = (size_t)blockIdx.x * 128;
    const size_t brow0 = (size_t)blockIdx.y * 64;

    const int sr  = lane >> 3;
    const int sc  = lane & 7;
    const int scg = sc ^ sr;

    f32x4 acc[4][2];
    #pragma unroll
    for (int mi = 0; mi < 4; ++mi)
        #pragma unroll
        for (int ni = 0; ni < 2; ++ni) acc[mi][ni] = (f32x4){0.f, 0.f, 0.f, 0.f};

    const int NT = K >> 6;

    auto STAGE = [&](int u, int k0) {
        short* As = smem[u];
        short* Bs = smem[u] + 128 * 64;
        #pragma unroll
        for (int i = 0; i < 4; ++i) {
            const int rg = w * 4 + i;
            gload_lds16(A + (arow0 + rg * 8 + sr) * K + k0 + scg * 8,
                        &As[rg * 8 * 64]);
        }
        #pragma unroll
        for (int i = 0; i < 2; ++i) {
            const int rg = w * 2 + i;
            gload_lds16(BT + (brow0 + rg * 8 + sr) * K + k0 + scg * 8,
                        &Bs[rg * 8 * 64]);
        }
    };

    STAGE(0, 0);
    __syncthreads();
    int cur = 0;

    for (int t = 0; t < NT; ++t) {
        if (t + 1 < NT) STAGE(cur ^ 1, (t + 1) << 6);
        const short* As = smem[cur];
        const short* Bs = smem[cur] + 128 * 64;

        #pragma unroll
        for (int dk = 0; dk < 2; ++dk) {
            short8 af[4], bf[2];
            #pragma unroll
            for (int mi = 0; mi < 4; ++mi) {
                const int r = wm * 64 + mi * 16 + lq;
                af[mi] = *reinterpret_cast<const short8*>(
                    &As[r * 64 + (((dk * 4 + lh) ^ (lq & 7)) * 8)]);
            }
            #pragma unroll
            for (int ni = 0; ni < 2; ++ni) {
                const int r = wn * 32 + ni * 16 + lq;
                bf[ni] = *reinterpret_cast<const short8*>(
                    &Bs[r * 64 + (((dk * 4 + lh) ^ (lq & 7)) * 8)]);
            }
            __builtin_amdgcn_s_setprio(1);
            #pragma unroll
            for (int mi = 0; mi < 4; ++mi)
                #pragma unroll
                for (int ni = 0; ni < 2; ++ni)
                    acc[mi][ni] = __builtin_amdgcn_mfma_f32_16x16x32_bf16(
                        af[mi], bf[ni], acc[mi][ni], 0, 0, 0);
            __builtin_amdgcn_s_setprio(0);
        }

        __syncthreads();
        cur ^= 1;
    }

    #pragma unroll
    for (int mi = 0; mi < 4; ++mi) {
        const size_t row = arow0 + wm * 64 + mi * 16 + lh * 4;
        #pragma unroll
        for (int ni = 0; ni < 2; ++ni) {
            const size_t col = brow0 + wn * 32 + ni * 16 + lq;
            #pragma unroll
            for (int i = 0; i < 4; ++i)
                C[(row + i) * N + col] = acc[mi][ni][i];
        }
    }
}

// ---------------------------------------------------------------------------
// bf16 MFMA flash attention — R14 champion verbatim.
// ---------------------------------------------------------------------------
__global__ __launch_bounds__(128) void attn_mfma(
    const short* __restrict__ q16, const short* __restrict__ k16,
    const short* __restrict__ vT16, short* __restrict__ att16, int B, int T) {
    __shared__ short Kt[64 * 64];
    __shared__ short Vt[64 * 64];

    const int tid  = threadIdx.x;
    const int lane = tid & 63;
    const int w    = tid >> 6;
    const int lq   = lane & 15;
    const int lh   = lane >> 4;

    const int idx = blockIdx.x;
    const int g   = idx & 7;
    const int j   = idx >> 3;
    const int b   = g >> 2;
    const int hk  = g & 3;
    const int qs  = (T >> 5) - 1 - (j >> 2);
    const int h   = hk * 4 + (j & 3);
    const int t0w = qs * 32 + w * 16;
    const int nt  = (qs >> 1) + 1;
    const bool evenq = !(qs & 1);

    const short* qrow = q16 + ((size_t)(b * 16 + h) * T + t0w + lq) * 64;
    const short8 qf0 = *reinterpret_cast<const short8*>(qrow + lh * 8);
    const short8 qf1 = *reinterpret_cast<const short8*>(qrow + 32 + lh * 8);

    const short* kgbase = k16 + (size_t)(b * 4 + hk) * T * 64;
    const short* vgbase = vT16 + (size_t)(b * 4 + hk) * 64 * T;

    const int sr  = lane >> 3;
    const int sc  = lane & 7;
    const int scg = sc ^ sr;

    short8 ones;
    #pragma unroll
    for (int i = 0; i < 8; ++i) ones[i] = (short)0x3F80;

    f32x4 yacc[4];
    #pragma unroll
    for (int dt = 0; dt < 4; ++dt) yacc[dt] = (f32x4){0.f, 0.f, 0.f, 0.f};
    f32x4 lacc = (f32x4){0.f, 0.f, 0.f, 0.f};

    for (int ti = 0; ti < nt; ++ti) {
        const int s0 = ti * 64;
        const bool last = (ti == nt - 1);
        const int kmax = (last && evenq) ? 2 : 4;
        __syncthreads();
        #pragma unroll
        for (int p2 = 0; p2 < 4; ++p2) {
            const int r = w * 32 + p2 * 8 + sr;
            gload_lds16(kgbase + (size_t)(s0 + r) * 64 + scg * 8,
                        &Kt[(w * 32 + p2 * 8) * 64]);
            gload_lds16(vgbase + (size_t)r * T + s0 + scg * 8,
                        &Vt[(w * 32 + p2 * 8) * 64]);
        }
        __syncthreads();

        f32x4 st[4];
        __builtin_amdgcn_s_setprio(1);
        #pragma unroll
        for (int ks = 0; ks < 4; ++ks) if (ks < kmax) {
            f32x4 a1 = (f32x4){0.f, 0.f, 0.f, 0.f};
            #pragma unroll
            for (int dk = 0; dk < 2; ++dk) {
                const short8 kfr = *reinterpret_cast<const short8*>(
                    (char*)Kt + (ks * 16 + lq) * 128 +
                    (((dk * 4 + lh) ^ (lq & 7)) * 16));
                a1 = __builtin_amdgcn_mfma_f32_16x16x32_bf16(
                    kfr, dk ? qf1 : qf0, a1, 0, 0, 0);
            }
            st[ks] = a1;
        }
        __builtin_amdgcn_s_setprio(0);

        if (last) {
            const int rloc = (qs & 1) * 32 + w * 16 + lq;
            #pragma unroll
            for (int ks = 0; ks < 4; ++ks) if (ks < kmax)
                #pragma unroll
                for (int i2 = 0; i2 < 4; ++i2)
                    if (ks * 16 + lh * 4 + i2 > rloc)
                        st[ks][i2] = -1e30f;
        }

        union { short8 s8; __hip_bfloat162 h2[4]; } pf[2];
        #pragma unroll
        for (int ks2 = 0; ks2 < 2; ++ks2) if (ks2 * 2 < kmax) {
            #pragma unroll
            for (int ks = 2 * ks2; ks < 2 * ks2 + 2; ++ks)
                #pragma unroll
                for (int i2 = 0; i2 < 4; ++i2)
                    st[ks][i2] = exp2f(st[ks][i2]);
            pf[ks2].h2[0] = __float22bfloat162_rn(float2{st[2 * ks2][0], st[2 * ks2][1]});
            pf[ks2].h2[1] = __float22bfloat162_rn(float2{st[2 * ks2][2], st[2 * ks2][3]});
            pf[ks2].h2[2] = __float22bfloat162_rn(float2{st[2 * ks2 + 1][0], st[2 * ks2 + 1][1]});
            pf[ks2].h2[3] = __float22bfloat162_rn(float2{st[2 * ks2 + 1][2], st[2 * ks2 + 1][3]});
        }

        __builtin_amdgcn_s_setprio(1);
        #pragma unroll
        for (int ks2 = 0; ks2 < 2; ++ks2) if (ks2 * 2 < kmax)
            lacc = __builtin_amdgcn_mfma_f32_16x16x32_bf16(ones, pf[ks2].s8, lacc, 0, 0, 0);
        #pragma unroll
        for (int dt = 0; dt < 4; ++dt) {
            const int rb = (dt * 16 + lq) * 128;
            const int sw = lq & 7;
            #pragma unroll
            for (int ks2 = 0; ks2 < 2; ++ks2) if (ks2 * 2 < kmax) {
                const short8 vf = *reinterpret_cast<const short8*>(
                    (const char*)Vt + rb + (((ks2 * 4 + lh) ^ sw) * 16));
                yacc[dt] = __builtin_amdgcn_mfma_f32_16x16x32_bf16(
                    vf, pf[ks2].s8, yacc[dt], 0, 0, 0);
            }
        }
        __builtin_amdgcn_s_setprio(0);
    }

    const float inv = 1.f / lacc[0];
    short* orow = att16 + (((size_t)b * T + t0w + lq) * 16 + h) * 64;
    #pragma unroll
    for (int dt = 0; dt < 4; ++dt) {
        short4v o;
        o[0] = f2bf(yacc[dt][0] * inv);
        o[1] = f2bf(yacc[dt][1] * inv);
        o[2] = f2bf(yacc[dt][2] * inv);
        o[3] = f2bf(yacc[dt][3] * inv);
        *reinterpret_cast<short4v*>(orow + dt * 16 + lh * 4) = o;
    }
}

// ---------------------------------------------------------------------------
extern "C" void kernel_launch(void* const* d_in, const int* in_sizes, int n_in,
                              void* d_out, int out_size, void* d_ws, size_t ws_size,
                              hipStream_t stream) {
    const float* x    = (const float*)d_in[0];
    const float* cosb = (const float*)d_in[1];
    const float* sinb = (const float*)d_in[2];
    const float* Wq   = (const float*)d_in[3];
    const float* Wk   = (const float*)d_in[4];
    const float* Wv   = (const float*)d_in[5];
    const float* Wo   = (const float*)d_in[6];
    float* out = (float*)d_out;

    const int B = 2, T = 2048;
    const int M = B * T;   // 4096
    const size_t MB = 1 << 20;

    // workspace (38 MB):
    //  [0,8M)   att16 bf16 [4096][1024]
    //  [8,16M)  q16 bf16 [B,16,T,64]
    //  [16,18M) k16 bf16 [B,4,T,64]
    //  [18,20M) vT16 bf16 [B,4,64,T]
    //  [24,32M) x16 bf16 [4096][1024]
    //  [32,35M) WT bf16 [1536][1024]
    //  [36,38M) WoT bf16 [1024][1024]
    char* wsb = (char*)d_ws;
    short* att16 = (short*)(wsb);
    short* q16   = (short*)(wsb + 8 * MB);
    short* k16   = (short*)(wsb + 16 * MB);
    short* vT16  = (short*)(wsb + 18 * MB);
    short* x16   = (short*)(wsb + 24 * MB);
    short* WT    = (short*)(wsb + 32 * MB);
    short* WoT   = (short*)(wsb + 36 * MB);

    // x cast + all weight transposes, one dispatch
    prep_inputs<<<2048 + 640, 256, 0, stream>>>(x, Wq, Wk, Wv, Wo,
                                                x16, WT, WoT, M * 1024 / 8);

    // fused QKV GEMM + rope/rms/v-transpose epilogue: grid (M/128, 24)
    gemm_qkv_fused<<<dim3(M / 128, 1536 / 64), 256, 0, stream>>>(
        x16, WT, cosb, sinb, q16, k16, vT16, B, T);

    // flash attention (R14 champion)
    attn_mfma<<<dim3((T / 32) * 16 * B), 128, 0, stream>>>(q16, k16, vT16, att16, B, T);

    // Wo GEMM: f32 output
    gemm_wo<<<dim3(M / 128, 1024 / 64), 256, 0, stream>>>(
        att16, WoT, out, M, 1024, 1024);
}

// Round 18
// 94.921 us; speedup vs baseline: 2.1534x; 1.0809x over previous
//
#include <hip/hip_runtime.h>
#include <hip/hip_bf16.h>
#include <math.h>

#define EPS 1e-6f
#define LOG2E 1.44269504088896340736f

typedef __attribute__((ext_vector_type(8))) short short8;
typedef __attribute__((ext_vector_type(4))) short short4v;
typedef __attribute__((ext_vector_type(4))) float f32x4;

// f32 -> bf16 (round-to-nearest-even)
static __device__ __forceinline__ short f2bf(float x) {
    unsigned u = __builtin_bit_cast(unsigned, x);
    u += 0x7fffu + ((u >> 16) & 1u);
    return (short)(u >> 16);
}
// bf16 -> f32
static __device__ __forceinline__ float bf2f(short s) {
    unsigned u = ((unsigned)(unsigned short)s) << 16;
    return __builtin_bit_cast(float, u);
}

typedef __attribute__((address_space(1))) const void gvoid_t;
typedef __attribute__((address_space(3))) void lvoid_t;
static __device__ __forceinline__ void gload_lds16(const void* g, void* l) {
    __builtin_amdgcn_global_load_lds((gvoid_t*)g, (lvoid_t*)l, 16, 0, 0);
}

// ---------------------------------------------------------------------------
// Combined input prep: x cast (blocks [0,2048)) + all 4 weight transposes
// (blocks [2048, 2688)) in one dispatch.
// ---------------------------------------------------------------------------
__global__ __launch_bounds__(256) void prep_inputs(
    const float* __restrict__ x, const float* __restrict__ Wq,
    const float* __restrict__ Wk, const float* __restrict__ Wv,
    const float* __restrict__ Wo, short* __restrict__ x16,
    short* __restrict__ WT, short* __restrict__ WoT, int n8) {
    if ((int)blockIdx.x < 2048) {
        const int i = blockIdx.x * 256 + threadIdx.x;
        if (i >= n8) return;
        const float4 a = reinterpret_cast<const float4*>(x)[2 * i];
        const float4 b = reinterpret_cast<const float4*>(x)[2 * i + 1];
        short8 o;
        o[0] = f2bf(a.x); o[1] = f2bf(a.y); o[2] = f2bf(a.z); o[3] = f2bf(a.w);
        o[4] = f2bf(b.x); o[5] = f2bf(b.y); o[6] = f2bf(b.z); o[7] = f2bf(b.w);
        reinterpret_cast<short8*>(x16)[i] = o;
        return;
    }
    __shared__ short tl[64][65];
    int t = blockIdx.x - 2048;
    const float* src; short* dst; int N, nx;
    if (t < 256)      { src = Wq; dst = WT;                N = 1024; nx = 16; }
    else if (t < 320) { src = Wk; dst = WT + 1024 * 1024;  N = 256;  nx = 4;  t -= 256; }
    else if (t < 384) { src = Wv; dst = WT + 1280 * 1024;  N = 256;  nx = 4;  t -= 320; }
    else              { src = Wo; dst = WoT;               N = 1024; nx = 16; t -= 384; }
    const int n0 = (t % nx) * 64, k0 = (t / nx) * 64;
    const int tid = threadIdx.x;

    #pragma unroll
    for (int i = 0; i < 4; ++i) {
        const int kr = (tid >> 4) + i * 16;
        const int c4 = (tid & 15) * 4;
        const float4 v = *reinterpret_cast<const float4*>(
            &src[(size_t)(k0 + kr) * N + n0 + c4]);
        tl[kr][c4 + 0] = f2bf(v.x);
        tl[kr][c4 + 1] = f2bf(v.y);
        tl[kr][c4 + 2] = f2bf(v.z);
        tl[kr][c4 + 3] = f2bf(v.w);
    }
    __syncthreads();

    const int nr  = tid >> 2;
    const int kc0 = (tid & 3) * 16;
    short tmp[16];
    #pragma unroll
    for (int j = 0; j < 16; ++j) tmp[j] = tl[kc0 + j][nr];
    short8* outp = reinterpret_cast<short8*>(&dst[(size_t)(n0 + nr) * 1024 + k0 + kc0]);
    outp[0] = *reinterpret_cast<short8*>(&tmp[0]);
    outp[1] = *reinterpret_cast<short8*>(&tmp[8]);
}

// ---------------------------------------------------------------------------
// FUSED QKV GEMM + rope/rms/v-transpose epilogue (R17), with the rope
// epilogue parallelized: 2 rows/iteration (32 lanes each), 5-step half-wave
// reduce, no divergent lane<32 select. 16 iterations instead of 32.
// ---------------------------------------------------------------------------
__global__ __launch_bounds__(256) void gemm_qkv_fused(
    const short* __restrict__ A, const short* __restrict__ BT,
    const float* __restrict__ cosb, const float* __restrict__ sinb,
    short* __restrict__ q16, short* __restrict__ k16, short* __restrict__ vT,
    int B, int T) {
    __shared__ short smem[2][(128 + 64) * 64];   // As | Bs, 48KB

    const int K = 1024;
    const int tid  = threadIdx.x;
    const int lane = tid & 63;
    const int w    = tid >> 6;
    const int lq = lane & 15, lh = lane >> 4;
    const int wm = w >> 1,   wn = w & 1;
    const size_t arow0 = (size_t)blockIdx.x * 128;
    const size_t brow0 = (size_t)blockIdx.y * 64;

    const int sr  = lane >> 3;
    const int sc  = lane & 7;
    const int scg = sc ^ sr;

    f32x4 acc[4][2];
    #pragma unroll
    for (int mi = 0; mi < 4; ++mi)
        #pragma unroll
        for (int ni = 0; ni < 2; ++ni) acc[mi][ni] = (f32x4){0.f, 0.f, 0.f, 0.f};

    const int NT = K >> 6;   // 16

    auto STAGE = [&](int u, int k0) {
        short* As = smem[u];
        short* Bs = smem[u] + 128 * 64;
        #pragma unroll
        for (int i = 0; i < 4; ++i) {
            const int rg = w * 4 + i;
            gload_lds16(A + (arow0 + rg * 8 + sr) * K + k0 + scg * 8,
                        &As[rg * 8 * 64]);
        }
        #pragma unroll
        for (int i = 0; i < 2; ++i) {
            const int rg = w * 2 + i;
            gload_lds16(BT + (brow0 + rg * 8 + sr) * K + k0 + scg * 8,
                        &Bs[rg * 8 * 64]);
        }
    };

    STAGE(0, 0);
    __syncthreads();
    int cur = 0;

    for (int t = 0; t < NT; ++t) {
        if (t + 1 < NT) STAGE(cur ^ 1, (t + 1) << 6);
        const short* As = smem[cur];
        const short* Bs = smem[cur] + 128 * 64;

        #pragma unroll
        for (int dk = 0; dk < 2; ++dk) {
            short8 af[4], bf[2];
            #pragma unroll
            for (int mi = 0; mi < 4; ++mi) {
                const int r = wm * 64 + mi * 16 + lq;
                af[mi] = *reinterpret_cast<const short8*>(
                    &As[r * 64 + (((dk * 4 + lh) ^ (lq & 7)) * 8)]);
            }
            #pragma unroll
            for (int ni = 0; ni < 2; ++ni) {
                const int r = wn * 32 + ni * 16 + lq;
                bf[ni] = *reinterpret_cast<const short8*>(
                    &Bs[r * 64 + (((dk * 4 + lh) ^ (lq & 7)) * 8)]);
            }
            __builtin_amdgcn_s_setprio(1);
            #pragma unroll
            for (int mi = 0; mi < 4; ++mi)
                #pragma unroll
                for (int ni = 0; ni < 2; ++ni)
                    acc[mi][ni] = __builtin_amdgcn_mfma_f32_16x16x32_bf16(
                        af[mi], bf[ni], acc[mi][ni], 0, 0, 0);
            __builtin_amdgcn_s_setprio(0);
        }

        __syncthreads();
        cur ^= 1;
    }

    // ---- epilogue: stash f32 tile [128][66-padded] in LDS ----
    float* fl = (float*)smem;   // 128*66*4 = 33792B <= 48KB
    #pragma unroll
    for (int mi = 0; mi < 4; ++mi) {
        const int row = wm * 64 + mi * 16 + lh * 4;
        #pragma unroll
        for (int ni = 0; ni < 2; ++ni) {
            const int col = wn * 32 + ni * 16 + lq;
            #pragma unroll
            for (int i = 0; i < 4; ++i)
                fl[(row + i) * 66 + col] = acc[mi][ni][i];
        }
    }
    __syncthreads();

    const int by = blockIdx.y;
    const int b  = (int)(arow0 / T);
    const int t0 = (int)(arow0 % T);

    if (by < 20) {
        // --- rope + rmsnorm; 2 rows/iter: lanes 0-31 -> even row,
        //     lanes 32-63 -> odd row; j = lane&31; 5-step half-wave reduce ---
        const int j  = lane & 31;
        const int rh = lane >> 5;                 // 0/1 -> row parity
        for (int rr = 0; rr < 16; ++rr) {
            const int row = w * 32 + rr * 2 + rh;
            const int t   = t0 + row;
            const float x1 = fl[row * 66 + j];
            const float x2 = fl[row * 66 + 32 + j];
            const float c = cosb[t * 32 + j];
            const float s = sinb[t * 32 + j];
            const float y1 = x1 * c + x2 * s;
            const float y2 = x2 * c - x1 * s;
            float ss = y1 * y1 + y2 * y2;
            #pragma unroll
            for (int m = 1; m < 32; m <<= 1) ss += __shfl_xor(ss, m);
            const float r = rsqrtf(ss * (1.0f / 64.0f) + EPS);
            if (by < 16) {
                short* o = q16 + ((size_t)(b * 16 + by) * T + t) * 64;
                o[j]      = f2bf(y1 * r * (0.125f * LOG2E));
                o[j + 32] = f2bf(y2 * r * (0.125f * LOG2E));
            } else {
                short* o = k16 + ((size_t)(b * 4 + (by - 16)) * T + t) * 64;
                o[j]      = f2bf(y1 * r);
                o[j + 32] = f2bf(y2 * r);
            }
        }
    } else {
        // --- v: cast + transpose + key-permute (two 64-row halves) ---
        const int kvh = by - 20;
        const int dim = tid >> 2;
        const int tq  = (tid & 3) * 16;
        const int hi  = (tq >> 4) & 1;
        const int a32 = tq & 32;
        short* orow = vT + ((size_t)(b * 4 + kvh) * 64 + dim) * T + t0;
        #pragma unroll
        for (int th = 0; th < 2; ++th) {
            short tmp[16];
            #pragma unroll
            for (int j2 = 0; j2 < 16; ++j2)
                tmp[j2] = f2bf(fl[(th * 64 + tq + j2) * 66 + dim]);
            #pragma unroll
            for (int g = 0; g < 4; ++g)
                *reinterpret_cast<short4v*>(orow + th * 64 + a32 + g * 8 + hi * 4) =
                    *reinterpret_cast<short4v*>(&tmp[g * 4]);
        }
    }
}

// ---------------------------------------------------------------------------
// bf16 MFMA GEMM (Wo): C f32 = A bf16 · B^T bf16. BK=64 (R16 proven).
// ---------------------------------------------------------------------------
__global__ __launch_bounds__(256) void gemm_wo(const short* __restrict__ A,
                                               const short* __restrict__ BT,
                                               float* __restrict__ C,
                                               int M, int N, int K) {
    __shared__ short smem[2][(128 + 64) * 64];

    const int tid  = threadIdx.x;
    const int lane = tid & 63;
    const int w    = tid >> 6;
    const int lq = lane & 15, lh = lane >> 4;
    const int wm = w >> 1,   wn = w & 1;
    const size_t arow0 = (size_t)blockIdx.x * 128;
    const size_t brow0 = (size_t)blockIdx.y * 64;

    const int sr  = lane >> 3;
    const int sc  = lane & 7;
    const int scg = sc ^ sr;

    f32x4 acc[4][2];
    #pragma unroll
    for (int mi = 0; mi < 4; ++mi)
        #pragma unroll
        for (int ni = 0; ni < 2; ++ni) acc[mi][ni] = (f32x4){0.f, 0.f, 0.f, 0.f};

    const int NT = K >> 6;

    auto STAGE = [&](int u, int k0) {
        short* As = smem[u];
        short* Bs = smem[u] + 128 * 64;
        #pragma unroll
        for (int i = 0; i < 4; ++i) {
            const int rg = w * 4 + i;
            gload_lds16(A + (arow0 + rg * 8 + sr) * K + k0 + scg * 8,
                        &As[rg * 8 * 64]);
        }
        #pragma unroll
        for (int i = 0; i < 2; ++i) {
            const int rg = w * 2 + i;
            gload_lds16(BT + (brow0 + rg * 8 + sr) * K + k0 + scg * 8,
                        &Bs[rg * 8 * 64]);
        }
    };

    STAGE(0, 0);
    __syncthreads();
    int cur = 0;

    for (int t = 0; t < NT; ++t) {
        if (t + 1 < NT) STAGE(cur ^ 1, (t + 1) << 6);
        const short* As = smem[cur];
        const short* Bs = smem[cur] + 128 * 64;

        #pragma unroll
        for (int dk = 0; dk < 2; ++dk) {
            short8 af[4], bf[2];
            #pragma unroll
            for (int mi = 0; mi < 4; ++mi) {
                const int r = wm * 64 + mi * 16 + lq;
                af[mi] = *reinterpret_cast<const short8*>(
                    &As[r * 64 + (((dk * 4 + lh) ^ (lq & 7)) * 8)]);
            }
            #pragma unroll
            for (int ni = 0; ni < 2; ++ni) {
                const int r = wn * 32 + ni * 16 + lq;
                bf[ni] = *reinterpret_cast<const short8*>(
                    &Bs[r * 64 + (((dk * 4 + lh) ^ (lq & 7)) * 8)]);
            }
            __builtin_amdgcn_s_setprio(1);
            #pragma unroll
            for (int mi = 0; mi < 4; ++mi)
                #pragma unroll
                for (int ni = 0; ni < 2; ++ni)
                    acc[mi][ni] = __builtin_amdgcn_mfma_f32_16x16x32_bf16(
                        af[mi], bf[ni], acc[mi][ni], 0, 0, 0);
            __builtin_amdgcn_s_setprio(0);
        }

        __syncthreads();
        cur ^= 1;
    }

    #pragma unroll
    for (int mi = 0; mi < 4; ++mi) {
        const size_t row = arow0 + wm * 64 + mi * 16 + lh * 4;
        #pragma unroll
        for (int ni = 0; ni < 2; ++ni) {
            const size_t col = brow0 + wn * 32 + ni * 16 + lq;
            #pragma unroll
            for (int i = 0; i < 4; ++i)
                C[(row + i) * N + col] = acc[mi][ni][i];
        }
    }
}

// ---------------------------------------------------------------------------
// bf16 MFMA flash attention — R14 champion verbatim.
// ---------------------------------------------------------------------------
__global__ __launch_bounds__(128) void attn_mfma(
    const short* __restrict__ q16, const short* __restrict__ k16,
    const short* __restrict__ vT16, short* __restrict__ att16, int B, int T) {
    __shared__ short Kt[64 * 64];
    __shared__ short Vt[64 * 64];

    const int tid  = threadIdx.x;
    const int lane = tid & 63;
    const int w    = tid >> 6;
    const int lq   = lane & 15;
    const int lh   = lane >> 4;

    const int idx = blockIdx.x;
    const int g   = idx & 7;
    const int j   = idx >> 3;
    const int b   = g >> 2;
    const int hk  = g & 3;
    const int qs  = (T >> 5) - 1 - (j >> 2);
    const int h   = hk * 4 + (j & 3);
    const int t0w = qs * 32 + w * 16;
    const int nt  = (qs >> 1) + 1;
    const bool evenq = !(qs & 1);

    const short* qrow = q16 + ((size_t)(b * 16 + h) * T + t0w + lq) * 64;
    const short8 qf0 = *reinterpret_cast<const short8*>(qrow + lh * 8);
    const short8 qf1 = *reinterpret_cast<const short8*>(qrow + 32 + lh * 8);

    const short* kgbase = k16 + (size_t)(b * 4 + hk) * T * 64;
    const short* vgbase = vT16 + (size_t)(b * 4 + hk) * 64 * T;

    const int sr  = lane >> 3;
    const int sc  = lane & 7;
    const int scg = sc ^ sr;

    short8 ones;
    #pragma unroll
    for (int i = 0; i < 8; ++i) ones[i] = (short)0x3F80;

    f32x4 yacc[4];
    #pragma unroll
    for (int dt = 0; dt < 4; ++dt) yacc[dt] = (f32x4){0.f, 0.f, 0.f, 0.f};
    f32x4 lacc = (f32x4){0.f, 0.f, 0.f, 0.f};

    for (int ti = 0; ti < nt; ++ti) {
        const int s0 = ti * 64;
        const bool last = (ti == nt - 1);
        const int kmax = (last && evenq) ? 2 : 4;
        __syncthreads();
        #pragma unroll
        for (int p2 = 0; p2 < 4; ++p2) {
            const int r = w * 32 + p2 * 8 + sr;
            gload_lds16(kgbase + (size_t)(s0 + r) * 64 + scg * 8,
                        &Kt[(w * 32 + p2 * 8) * 64]);
            gload_lds16(vgbase + (size_t)r * T + s0 + scg * 8,
                        &Vt[(w * 32 + p2 * 8) * 64]);
        }
        __syncthreads();

        f32x4 st[4];
        __builtin_amdgcn_s_setprio(1);
        #pragma unroll
        for (int ks = 0; ks < 4; ++ks) if (ks < kmax) {
            f32x4 a1 = (f32x4){0.f, 0.f, 0.f, 0.f};
            #pragma unroll
            for (int dk = 0; dk < 2; ++dk) {
                const short8 kfr = *reinterpret_cast<const short8*>(
                    (char*)Kt + (ks * 16 + lq) * 128 +
                    (((dk * 4 + lh) ^ (lq & 7)) * 16));
                a1 = __builtin_amdgcn_mfma_f32_16x16x32_bf16(
                    kfr, dk ? qf1 : qf0, a1, 0, 0, 0);
            }
            st[ks] = a1;
        }
        __builtin_amdgcn_s_setprio(0);

        if (last) {
            const int rloc = (qs & 1) * 32 + w * 16 + lq;
            #pragma unroll
            for (int ks = 0; ks < 4; ++ks) if (ks < kmax)
                #pragma unroll
                for (int i2 = 0; i2 < 4; ++i2)
                    if (ks * 16 + lh * 4 + i2 > rloc)
                        st[ks][i2] = -1e30f;
        }

        union { short8 s8; __hip_bfloat162 h2[4]; } pf[2];
        #pragma unroll
        for (int ks2 = 0; ks2 < 2; ++ks2) if (ks2 * 2 < kmax) {
            #pragma unroll
            for (int ks = 2 * ks2; ks < 2 * ks2 + 2; ++ks)
                #pragma unroll
                for (int i2 = 0; i2 < 4; ++i2)
                    st[ks][i2] = exp2f(st[ks][i2]);
            pf[ks2].h2[0] = __float22bfloat162_rn(float2{st[2 * ks2][0], st[2 * ks2][1]});
            pf[ks2].h2[1] = __float22bfloat162_rn(float2{st[2 * ks2][2], st[2 * ks2][3]});
            pf[ks2].h2[2] = __float22bfloat162_rn(float2{st[2 * ks2 + 1][0], st[2 * ks2 + 1][1]});
            pf[ks2].h2[3] = __float22bfloat162_rn(float2{st[2 * ks2 + 1][2], st[2 * ks2 + 1][3]});
        }

        __builtin_amdgcn_s_setprio(1);
        #pragma unroll
        for (int ks2 = 0; ks2 < 2; ++ks2) if (ks2 * 2 < kmax)
            lacc = __builtin_amdgcn_mfma_f32_16x16x32_bf16(ones, pf[ks2].s8, lacc, 0, 0, 0);
        #pragma unroll
        for (int dt = 0; dt < 4; ++dt) {
            const int rb = (dt * 16 + lq) * 128;
            const int sw = lq & 7;
            #pragma unroll
            for (int ks2 = 0; ks2 < 2; ++ks2) if (ks2 * 2 < kmax) {
                const short8 vf = *reinterpret_cast<const short8*>(
                    (const char*)Vt + rb + (((ks2 * 4 + lh) ^ sw) * 16));
                yacc[dt] = __builtin_amdgcn_mfma_f32_16x16x32_bf16(
                    vf, pf[ks2].s8, yacc[dt], 0, 0, 0);
            }
        }
        __builtin_amdgcn_s_setprio(0);
    }

    const float inv = 1.f / lacc[0];
    short* orow = att16 + (((size_t)b * T + t0w + lq) * 16 + h) * 64;
    #pragma unroll
    for (int dt = 0; dt < 4; ++dt) {
        short4v o;
        o[0] = f2bf(yacc[dt][0] * inv);
        o[1] = f2bf(yacc[dt][1] * inv);
        o[2] = f2bf(yacc[dt][2] * inv);
        o[3] = f2bf(yacc[dt][3] * inv);
        *reinterpret_cast<short4v*>(orow + dt * 16 + lh * 4) = o;
    }
}

// ---------------------------------------------------------------------------
extern "C" void kernel_launch(void* const* d_in, const int* in_sizes, int n_in,
                              void* d_out, int out_size, void* d_ws, size_t ws_size,
                              hipStream_t stream) {
    const float* x    = (const float*)d_in[0];
    const float* cosb = (const float*)d_in[1];
    const float* sinb = (const float*)d_in[2];
    const float* Wq   = (const float*)d_in[3];
    const float* Wk   = (const float*)d_in[4];
    const float* Wv   = (const float*)d_in[5];
    const float* Wo   = (const float*)d_in[6];
    float* out = (float*)d_out;

    const int B = 2, T = 2048;
    const int M = B * T;   // 4096
    const size_t MB = 1 << 20;

    char* wsb = (char*)d_ws;
    short* att16 = (short*)(wsb);
    short* q16   = (short*)(wsb + 8 * MB);
    short* k16   = (short*)(wsb + 16 * MB);
    short* vT16  = (short*)(wsb + 18 * MB);
    short* x16   = (short*)(wsb + 24 * MB);
    short* WT    = (short*)(wsb + 32 * MB);
    short* WoT   = (short*)(wsb + 36 * MB);

    // x cast + all weight transposes, one dispatch
    prep_inputs<<<2048 + 640, 256, 0, stream>>>(x, Wq, Wk, Wv, Wo,
                                                x16, WT, WoT, M * 1024 / 8);

    // fused QKV GEMM + rope/rms/v-transpose epilogue: grid (M/128, 24)
    gemm_qkv_fused<<<dim3(M / 128, 1536 / 64), 256, 0, stream>>>(
        x16, WT, cosb, sinb, q16, k16, vT16, B, T);

    // flash attention (R14 champion)
    attn_mfma<<<dim3((T / 32) * 16 * B), 128, 0, stream>>>(q16, k16, vT16, att16, B, T);

    // Wo GEMM: f32 output
    gemm_wo<<<dim3(M / 128, 1024 / 64), 256, 0, stream>>>(
        att16, WoT, out, M, 1024, 1024);
}